// Round 14
// baseline (828.273 us; speedup 1.0000x reference)
//
#include <hip/hip_runtime.h>
#include <hip/hip_bf16.h>
#include <stdint.h>

// LSTM-CRF forward loss. B=128 L=256 V=6000 E=128 RV=300 RD=100 H=256 C=33
// DIN=428 (pad to 448). Pipeline:
//   pack_weights -> pack_A -> gemm_xg (jf-paired X2 layout, b32 pk-stores)
//   -> lstm_recur (32 wg x 512 thr, r10 structure; Whh pinned; uint4 px)
//   -> emis_k -> golden_k -> crf_k -> fin_k

typedef unsigned short u16;
typedef __attribute__((ext_vector_type(8))) __bf16 bf16x8;
typedef __attribute__((ext_vector_type(4))) float f32x4;

struct __align__(8) u16x4 { u16 x, y, z, w; };

typedef const void __attribute__((address_space(1))) gas_t;
typedef void __attribute__((address_space(3))) las_t;

static __device__ __forceinline__ void gload16(const void* g, void* l) {
  __builtin_amdgcn_global_load_lds((gas_t*)g, (las_t*)l, 16, 0, 0);
}

static __device__ __forceinline__ u16 f2b(float x) {
  uint32_t u = __builtin_bit_cast(uint32_t, x);
  uint32_t r = u + 0x7fffu + ((u >> 16) & 1u);
  return (u16)(r >> 16);
}
static __device__ __forceinline__ float b2lo(uint32_t u) {
  return __builtin_bit_cast(float, u << 16);
}
static __device__ __forceinline__ float b2hi(uint32_t u) {
  return __builtin_bit_cast(float, u & 0xffff0000u);
}
static __device__ __forceinline__ uint32_t pkbf16(float lo, float hi) {
  uint32_t w;
  asm("v_cvt_pk_bf16_f32 %0, %1, %2" : "=v"(w) : "v"(lo), "v"(hi));
  return w;
}
static __device__ __forceinline__ float sigf(float x) {
  return __builtin_amdgcn_rcpf(1.f + __expf(-x));
}
static __device__ __forceinline__ float tanh_(float x) {
  return 1.f - 2.f * __builtin_amdgcn_rcpf(1.f + __expf(2.f * x));
}
static __device__ __forceinline__ f32x4 MFMA(bf16x8 a, bf16x8 b, f32x4 c) {
  return __builtin_amdgcn_mfma_f32_16x16x32_bf16(a, b, c, 0, 0, 0);
}

// ---------------- pack weights ----------------
// WihP[2048][448] bf16; bias[2048] f32 = bih+bhh; WclsP[48][512] bf16;
// WhhF8: fp8 e4m3 B-fragments, long-index ((d*8+v)*64 + gj*8+kf)*64 + lane,
//   gj = gate*2+jf; byte e: Whh_d[gate*256+v*32+jf*16+(lane&15)][kf*32+(lane>>4)*8+e]
__global__ __launch_bounds__(256) void pack_weights(
    const float* __restrict__ Wih_f, const float* __restrict__ Wih_b,
    const float* __restrict__ Whh_f, const float* __restrict__ Whh_b,
    const float* __restrict__ bih_f, const float* __restrict__ bhh_f,
    const float* __restrict__ bih_b, const float* __restrict__ bhh_b,
    const float* __restrict__ Wcls,
    u16* __restrict__ WihP, unsigned int* __restrict__ WhhF8,
    float* __restrict__ biasP, u16* __restrict__ WclsP) {
  int idx = blockIdx.x * 256 + threadIdx.x;
  if (idx < 917504) {                       // 2*1024*448
    int d = idx / 458752;
    int rem = idx - d * 458752;
    int r = rem / 448, k = rem - r * 448;
    const float* W = d ? Wih_b : Wih_f;
    WihP[idx] = (k < 428) ? f2b(W[r * 428 + k]) : (u16)0;
  } else if (idx < 919552) {                // bias 2048
    int j = idx - 917504;
    int r = j & 1023;
    biasP[j] = (j >> 10) ? (bih_b[r] + bhh_b[r]) : (bih_f[r] + bhh_f[r]);
  } else if (idx < 944128) {                // Wcls 48*512
    int j = idx - 919552;
    int r = j >> 9, k = j & 511;
    WclsP[j] = (r < 33) ? f2b(Wcls[r * 512 + k]) : (u16)0;
  } else if (idx < 1075200) {               // WhhF8: 131072 dwords
    int q = idx - 944128;
    int eh = q & 1, li = (q >> 1) & 63, fi = (q >> 7) & 63;
    int v = (q >> 13) & 7, dd = q >> 16;
    int l16 = li & 15, g = li >> 4;
    int kf = fi & 7, gj = fi >> 3;
    int gate = gj >> 1, jf = gj & 1;
    int row = gate * 256 + v * 32 + jf * 16 + l16;
    int col = kf * 32 + g * 8 + eh * 4;
    const float* W = dd ? Whh_b : Whh_f;
    float4 f = *(const float4*)(W + (size_t)row * 256 + col);
    unsigned int r01 = __builtin_amdgcn_cvt_pk_fp8_f32(f.x, f.y, 0u, false) & 0xffffu;
    unsigned int r23 = __builtin_amdgcn_cvt_pk_fp8_f32(f.z, f.w, 0u, false) & 0xffffu;
    WhhF8[q] = r01 | (r23 << 16);
  }
}

// ---------------- gather + pack A: [32768][448] bf16 ----------------
__global__ __launch_bounds__(256) void pack_A(const int* __restrict__ data,
    const int* __restrict__ onerad, const float* __restrict__ embed,
    const float* __restrict__ rad, u16* __restrict__ A) {
  int idx = blockIdx.x * 256 + threadIdx.x;
  int m = idx / 112;
  int c = idx - m * 112;
  int k0 = c * 4;
  float4 vv;
  if (k0 < 128)      vv = *(const float4*)(embed + (size_t)data[m] * 128 + k0);
  else if (k0 < 228) vv = *(const float4*)(rad + (size_t)onerad[m] * 100 + (k0 - 128));
  else if (k0 < 328) vv = *(const float4*)(rad + (size_t)onerad[32768 + m] * 100 + (k0 - 228));
  else if (k0 < 428) vv = *(const float4*)(rad + (size_t)onerad[65536 + m] * 100 + (k0 - 328));
  else               vv = make_float4(0.f, 0.f, 0.f, 0.f);
  u16x4 o4 = { f2b(vv.x), f2b(vv.y), f2b(vv.z), f2b(vv.w) };
  *(u16x4*)(A + (size_t)m * 448 + k0) = o4;
}

// ---------------- xg GEMM: X2 = jf-paired gate-major(A @ Wih^T + bias) ----------------
// X2 u16 layout per d (33554432 u16): idx = R*1024 + v*128 + l16*8 + gate*2 + jf,
// R = m*256+t; col = d*1024 + gate*256 + v*32 + jf*16 + l16. jf pairs are
// adjacent -> paired b32 stores in the epilogue; lstm reads uint4 (all 4
// gates, both jf) per lane.
__global__ __launch_bounds__(256) void gemm_xg(const u16* __restrict__ A,
    const u16* __restrict__ Bw, const float* __restrict__ bias,
    u16* __restrict__ X2) {
  __shared__ u16 As[4096];
  __shared__ u16 Bs[4096];
  int bid = blockIdx.x;
  int mt = bid >> 4, nt = bid & 15;
  int m0 = mt * 128, n0 = nt * 128;
  int tid = threadIdx.x;
  int w = tid >> 6, lane = tid & 63, l16 = lane & 15, g = lane >> 4;
  int wr = w >> 1, wc = w & 1;
  int srow = tid >> 2, sch = tid & 3;
  f32x4 zero4 = {0.f, 0.f, 0.f, 0.f};
  f32x4 acc[4][4];
#pragma unroll
  for (int i = 0; i < 4; ++i)
#pragma unroll
    for (int j = 0; j < 4; ++j) acc[i][j] = zero4;
  for (int kk = 0; kk < 14; ++kk) {
    int kb = kk * 32;
    gload16(A + (size_t)(m0 + srow) * 448 + kb + sch * 8, (char*)As + tid * 16);
    gload16(A + (size_t)(m0 + srow + 64) * 448 + kb + sch * 8, (char*)As + 4096 + tid * 16);
    gload16(Bw + (size_t)(n0 + srow) * 448 + kb + sch * 8, (char*)Bs + tid * 16);
    gload16(Bw + (size_t)(n0 + srow + 64) * 448 + kb + sch * 8, (char*)Bs + 4096 + tid * 16);
    __syncthreads();
    bf16x8 af[4], bfr[4];
#pragma unroll
    for (int i = 0; i < 4; ++i) {
      af[i]  = *(const bf16x8*)((const char*)As + (wr * 64 + i * 16 + l16) * 64 + g * 16);
      bfr[i] = *(const bf16x8*)((const char*)Bs + (wc * 64 + i * 16 + l16) * 64 + g * 16);
    }
#pragma unroll
    for (int i = 0; i < 4; ++i)
#pragma unroll
      for (int j = 0; j < 4; ++j)
        acc[i][j] = MFMA(af[i], bfr[j], acc[i][j]);
    __syncthreads();
  }
  float bv[4];
#pragma unroll
  for (int j = 0; j < 4; ++j) bv[j] = bias[n0 + wc * 64 + j * 16 + l16];
  int dd = n0 >> 10;
#pragma unroll
  for (int i = 0; i < 4; ++i)
#pragma unroll
    for (int jp = 0; jp < 2; ++jp) {
      int j0 = jp * 2;
      int c = (n0 + wc * 64 + j0 * 16 + l16) & 1023;   // jf=0 member
      int gate = c >> 8, vv = (c >> 5) & 7, lc = c & 15;
      size_t base = (size_t)dd * 33554432 + (size_t)vv * 128 + lc * 8 + gate * 2;
#pragma unroll
      for (int r = 0; r < 4; ++r) {
        int row = m0 + wr * 64 + i * 16 + g * 4 + r;
        *(unsigned int*)(X2 + base + (size_t)row * 1024) =
            pkbf16(acc[i][j0][r] + bv[j0], acc[i][j0 + 1][r] + bv[j0 + 1]);
      }
    }
}

// ---------------- LSTM recurrence: 32 blocks, one 8-row chunk each ----------------
// r10 structure (proven): 32 blocks (2 dir x 16 chunks of 8 rows) x 512 thr.
// Whh pinned (64 longs/lane -> AGPR file). MFMA M=16 tile, rows 8-15 zero.
// Activations lane-redistributed: lower 32 lanes jf0, upper jf1 via
// shfl_xor(32); px is a uint4 (4 gates x both jf), jf selected by lo32.
#define PIN(n) long q##n; \
  asm volatile("global_load_dwordx2 %0, %1, off" : "=v"(q##n) : "v"(wbase + (n) * 512));
#define MMG(acc, gj, bn) \
  acc[gj] = __builtin_amdgcn_mfma_f32_16x16x32_fp8_fp8(a, bn, acc[gj], 0, 0, 0);
#define KSTEP(acc, fr, kf, B0, B1, B2, B3, B4, B5, B6, B7) { \
  long a = fr[(kf) * 64 + lane]; \
  MMG(acc, 0, B0) MMG(acc, 1, B1) MMG(acc, 2, B2) MMG(acc, 3, B3) \
  MMG(acc, 4, B4) MMG(acc, 5, B5) MMG(acc, 6, B6) MMG(acc, 7, B7) }
#define MFMA_PHASE(acc, hf) { \
  const long* fr = (const long*)(hf); \
  acc[0] = zero4; acc[1] = zero4; acc[2] = zero4; acc[3] = zero4; \
  acc[4] = zero4; acc[5] = zero4; acc[6] = zero4; acc[7] = zero4; \
  KSTEP(acc, fr, 0, q0, q8,  q16, q24, q32, q40, q48, q56) \
  KSTEP(acc, fr, 1, q1, q9,  q17, q25, q33, q41, q49, q57) \
  KSTEP(acc, fr, 2, q2, q10, q18, q26, q34, q42, q50, q58) \
  KSTEP(acc, fr, 3, q3, q11, q19, q27, q35, q43, q51, q59) \
  KSTEP(acc, fr, 4, q4, q12, q20, q28, q36, q44, q52, q60) \
  KSTEP(acc, fr, 5, q5, q13, q21, q29, q37, q45, q53, q61) \
  KSTEP(acc, fr, 6, q6, q14, q22, q30, q38, q46, q54, q62) \
  KSTEP(acc, fr, 7, q7, q15, q23, q31, q39, q47, q55, q63) }
#define TRANS(acc, cst, hf, sb, px) { \
  _Pragma("unroll") \
  for (int r = 0; r < 4; ++r) { \
    float o0 = __shfl_xor(acc[1][r], 32); \
    float o1 = __shfl_xor(acc[3][r], 32); \
    float o2 = __shfl_xor(acc[5][r], 32); \
    float o3 = __shfl_xor(acc[7][r], 32); \
    float iv = lo32 ? (acc[0][r] + b2lo(px[r].x)) : (o0 + b2hi(px[r].x)); \
    float fv = lo32 ? (acc[2][r] + b2lo(px[r].y)) : (o1 + b2hi(px[r].y)); \
    float gv = lo32 ? (acc[4][r] + b2lo(px[r].z)) : (o2 + b2hi(px[r].z)); \
    float ov = lo32 ? (acc[6][r] + b2lo(px[r].w)) : (o3 + b2hi(px[r].w)); \
    float cn = sigf(fv) * cst[r] + sigf(iv) * tanh_(gv); \
    cst[r] = cn; \
    float hv = sigf(ov) * tanh_(cn); \
    ((unsigned char*)(hf))[fwoff + r * 8] = \
        (unsigned char)__builtin_amdgcn_cvt_pk_fp8_f32(hv, hv, 0u, false); \
    *(u16*)(sb[r] + voff_st) = f2b(hv); \
  } }
#define BUMP4(p, s) { p[0] += s; p[1] += s; p[2] += s; p[3] += s; }
#define LOADPX(px, pb) { \
  px[0] = *(const uint4*)(pb[0] + voff_px); \
  px[1] = *(const uint4*)(pb[1] + voff_px); \
  px[2] = *(const uint4*)(pb[2] + voff_px); \
  px[3] = *(const uint4*)(pb[3] + voff_px); }
#define FENCE { __builtin_amdgcn_sched_barrier(0); \
  asm volatile("s_waitcnt lgkmcnt(0)"); \
  __builtin_amdgcn_s_barrier(); \
  __builtin_amdgcn_sched_barrier(0); }

__global__ __launch_bounds__(512, 1) void lstm_recur(const u16* __restrict__ xg,
    const unsigned char* __restrict__ WhhF8, u16* __restrict__ outh) {
  __shared__ unsigned char hfA[2][4096];
  int blk = blockIdx.x;
  int d = blk >> 4, c8 = blk & 15;
  int rowA0 = c8 * 8;
  int tid = threadIdx.x;
  int v = tid >> 6, lane = tid & 63, l16 = lane & 15, g = lane >> 4;
  int jfL = g >> 1, gl = g & 1;
  bool lo32 = (lane < 32);

  const char* wbase = (const char*)WhhF8 + ((size_t)(d * 8 + v) * 4096 + lane) * 8;
  PIN(0)  PIN(1)  PIN(2)  PIN(3)  PIN(4)  PIN(5)  PIN(6)  PIN(7)
  PIN(8)  PIN(9)  PIN(10) PIN(11) PIN(12) PIN(13) PIN(14) PIN(15)
  PIN(16) PIN(17) PIN(18) PIN(19) PIN(20) PIN(21) PIN(22) PIN(23)
  PIN(24) PIN(25) PIN(26) PIN(27) PIN(28) PIN(29) PIN(30) PIN(31)
  PIN(32) PIN(33) PIN(34) PIN(35) PIN(36) PIN(37) PIN(38) PIN(39)
  PIN(40) PIN(41) PIN(42) PIN(43) PIN(44) PIN(45) PIN(46) PIN(47)
  PIN(48) PIN(49) PIN(50) PIN(51) PIN(52) PIN(53) PIN(54) PIN(55)
  PIN(56) PIN(57) PIN(58) PIN(59) PIN(60) PIN(61) PIN(62) PIN(63)

  for (int i = tid; i < 2048; i += 512) ((int*)hfA)[i] = 0;

  int t0 = d ? 255 : 0;
  int tpx = d ? -2048 : 2048;    // bytes per t-step in X2 (1024 u16/row-step)
  int tob = d ? -1024 : 1024;    // bytes per t-step in outh (512 u16)

  const char* X2b = (const char*)xg + (size_t)d * 67108864;
  char* outhb = (char*)outh;
  const char* pbA[4];
  char* sbA[4];
#pragma unroll
  for (int r = 0; r < 4; ++r) {
    pbA[r] = X2b + ((size_t)(rowA0 + gl * 4 + r) * 256 + t0) * 2048;
    sbA[r] = outhb + (((size_t)(rowA0 + gl * 4 + r) * 256 + t0) * 512 + d * 256) * 2;
  }
  int voff_px = v * 256 + l16 * 16;                       // uint4: (v*128+l16*8)*2
  int voff_st = (v * 32 + jfL * 16 + l16) * 2;
  int fwoff = (v * 64 + jfL * 32 + (l16 >> 3) * 16 + gl * 4) * 8 + (l16 & 7);

  uint4 pxA[4];
  LOADPX(pxA, pbA);

  asm volatile("s_waitcnt vmcnt(0)" ::: "memory");
  __builtin_amdgcn_sched_barrier(0);

  f32x4 zero4 = {0.f, 0.f, 0.f, 0.f};
  f32x4 cstA = zero4;
  f32x4 accA[8];
  __syncthreads();

#pragma unroll 1
  for (int tt = 0; tt < 256; ++tt) {
    int p = tt & 1;
    MFMA_PHASE(accA, &hfA[p][0]);
    {
      unsigned char* hf = &hfA[p ^ 1][0];
      TRANS(accA, cstA, hf, sbA, pxA);
    }
    BUMP4(sbA, tob); BUMP4(pbA, tpx);
    LOADPX(pxA, pbA);
    FENCE;
  }
}

// ---------------- emission: [32768][33] f32 = outh @ Wcls^T + bcls ----------------
__global__ __launch_bounds__(256) void emis_k(const u16* __restrict__ outh,
    const u16* __restrict__ WclsP, const float* __restrict__ bcls,
    float* __restrict__ emiB) {
  int tid = threadIdx.x;
  int w = tid >> 6, lane = tid & 63, l16 = lane & 15, g = lane >> 4;
  int mrow = blockIdx.x * 64 + w * 16;
  f32x4 zero4 = {0.f, 0.f, 0.f, 0.f};
  f32x4 acc[3] = {zero4, zero4, zero4};
#pragma unroll
  for (int kf = 0; kf < 16; ++kf) {
    bf16x8 a = *(const bf16x8*)(outh + (size_t)(mrow + l16) * 512 + kf * 32 + g * 8);
#pragma unroll
    for (int nf = 0; nf < 3; ++nf) {
      bf16x8 bb = *(const bf16x8*)(WclsP + (size_t)(nf * 16 + l16) * 512 + kf * 32 + g * 8);
      acc[nf] = MFMA(a, bb, acc[nf]);
    }
  }
#pragma unroll
  for (int nf = 0; nf < 3; ++nf) {
    int c = nf * 16 + l16;
    if (c < 33) {
      float bc = bcls[c];
#pragma unroll
      for (int r = 0; r < 4; ++r)
        emiB[(size_t)(mrow + g * 4 + r) * 33 + c] = acc[nf][r] + bc;
    }
  }
}

// ---------------- golden path score per batch row ----------------
__global__ __launch_bounds__(256) void golden_k(const int* __restrict__ tag,
    const float* __restrict__ emiB, const float* __restrict__ T,
    float* __restrict__ gpart) {
  int b = blockIdx.x, l = threadIdx.x;
  int tg = tag[b * 256 + l];
  float val = 0.f;
  if (tg != 0) {
    int prev = (l == 0) ? 31 : tag[b * 256 + l - 1];
    val = emiB[(size_t)(b * 256 + l) * 33 + tg] + T[prev * 33 + tg];
  }
#pragma unroll
  for (int o = 32; o > 0; o >>= 1) val += __shfl_down(val, o);
  __shared__ float red[4];
  if ((threadIdx.x & 63) == 0) red[threadIdx.x >> 6] = val;
  __syncthreads();
  if (threadIdx.x == 0) gpart[b] = red[0] + red[1] + red[2] + red[3];
}

// ---------------- CRF forward (logsumexp scan), 1 wave per batch row ----------------
__global__ __launch_bounds__(64) void crf_k(const int* __restrict__ tag,
    const float* __restrict__ emiB, const float* __restrict__ T,
    float* __restrict__ endsc) {
  int b = blockIdx.x;
  int lane = threadIdx.x;
  __shared__ float Ts[1089];
  __shared__ float sc[33];
  for (int i = lane; i < 1089; i += 64) Ts[i] = T[i];
  int cnt = 0;
  for (int i = lane; i < 256; i += 64) cnt += (tag[b * 256 + i] != 0) ? 1 : 0;
#pragma unroll
  for (int o = 1; o < 64; o <<= 1) cnt += __shfl_xor(cnt, o);
  int len = cnt;
  __syncthreads();
  int c = lane;
  float tcol[33];
  if (c < 33) {
#pragma unroll
    for (int p = 0; p < 33; ++p) tcol[p] = Ts[p * 33 + c];
    sc[c] = emiB[(size_t)(b * 256) * 33 + c] + tcol[31];   // START=31
  }
  __syncthreads();
#pragma unroll 1
  for (int t = 1; t < 256; ++t) {
    if (t >= len) break;
    float nv = 0.f;
    if (c < 33) {
      float ec = emiB[(size_t)(b * 256 + t) * 33 + c];
      float vb[33];
      float mx = -3.0e38f;
#pragma unroll
      for (int p = 0; p < 33; ++p) { vb[p] = sc[p] + tcol[p]; mx = fmaxf(mx, vb[p]); }
      float s = 0.f;
#pragma unroll
      for (int p = 0; p < 33; ++p) s += __expf(vb[p] - mx);
      nv = ec + mx + __logf(s);
    }
    __syncthreads();
    if (c < 33) sc[c] = nv;
    __syncthreads();
  }
  if (lane == 0) endsc[b] = sc[32];   // END=32
}

// ---------------- finalize ----------------
__global__ __launch_bounds__(64) void fin_k(const float* __restrict__ gpart,
    const float* __restrict__ endsc, float* __restrict__ out) {
  int l = threadIdx.x;
  float v = (endsc[l] - gpart[l]) + (endsc[l + 64] - gpart[l + 64]);
#pragma unroll
  for (int o = 32; o > 0; o >>= 1) v += __shfl_down(v, o);
  if (l == 0) out[0] = v / 128.f;
}

extern "C" void kernel_launch(void* const* d_in, const int* in_sizes, int n_in,
                              void* d_out, int out_size, void* d_ws, size_t ws_size,
                              hipStream_t stream) {
  const int*   batch_data   = (const int*)d_in[0];
  const int*   batch_onerad = (const int*)d_in[1];
  const int*   batch_tag    = (const int*)d_in[2];
  const float* embed        = (const float*)d_in[3];
  const float* rad_embed    = (const float*)d_in[4];
  const float* Wih_f = (const float*)d_in[5];
  const float* Whh_f = (const float*)d_in[6];
  const float* bih_f = (const float*)d_in[7];
  const float* bhh_f = (const float*)d_in[8];
  const float* Wih_b = (const float*)d_in[9];
  const float* Whh_b = (const float*)d_in[10];
  const float* bih_b = (const float*)d_in[11];
  const float* bhh_b = (const float*)d_in[12];
  const float* Wcls  = (const float*)d_in[13];
  const float* bcls  = (const float*)d_in[14];
  const float* trans = (const float*)d_in[15];

  // workspace layout (~203.9 MB)
  char* ws = (char*)d_ws;
  u16*   Apack = (u16*)  (ws + 0);            // 29360128
  u16*   X2    = (u16*)  (ws + 29360128);     // 134217728 (jf-paired xg)
  u16*   WihP  = (u16*)  (ws + 163577856);    // 1835008
  unsigned int* WhhF8 = (unsigned int*)(ws + 165412864); // 524288
  float* biasP = (float*)(ws + 165937152);    // 8192
  u16*   WclsP = (u16*)  (ws + 165945344);    // 49152
  u16*   outh  = (u16*)  (ws + 165994496);    // 33554432
  float* emiB  = (float*)(ws + 199548928);    // 4325376
  float* gpart = (float*)(ws + 203874304);    // 512
  float* endsc = (float*)(ws + 203874816);    // 512

  pack_weights<<<4200, 256, 0, stream>>>(Wih_f, Wih_b, Whh_f, Whh_b, bih_f, bhh_f,
                                         bih_b, bhh_b, Wcls, WihP, WhhF8, biasP, WclsP);
  pack_A<<<14336, 256, 0, stream>>>(batch_data, batch_onerad, embed, rad_embed, Apack);
  gemm_xg<<<4096, 256, 0, stream>>>(Apack, WihP, biasP, X2);
  lstm_recur<<<32, 512, 0, stream>>>(X2, (const unsigned char*)WhhF8, outh);
  emis_k<<<512, 256, 0, stream>>>(outh, WclsP, bcls, emiB);
  golden_k<<<128, 256, 0, stream>>>(batch_tag, emiB, trans, gpart);
  crf_k<<<128, 64, 0, stream>>>(batch_tag, emiB, trans, endsc);
  fin_k<<<1, 64, 0, stream>>>(gpart, endsc, (float*)d_out);
}

// Round 15
// 824.967 us; speedup vs baseline: 1.0040x; 1.0040x over previous
//
#include <hip/hip_runtime.h>
#include <hip/hip_bf16.h>
#include <stdint.h>

// LSTM-CRF forward loss. B=128 L=256 V=6000 E=128 RV=300 RD=100 H=256 C=33
// DIN=428 (pad to 448). Pipeline:
//   pack_all (weights+A) -> gemm_xg (jf-paired X2, b32 pk-stores)
//   -> lstm_recur (32 wg x 512 thr; Whh pinned; uint4 px)  [r14, proven]
//   -> emis_k -> crf2_k (LDS-resident emissions, golden fused, 4-way chains)
//   -> fin_k

typedef unsigned short u16;
typedef __attribute__((ext_vector_type(8))) __bf16 bf16x8;
typedef __attribute__((ext_vector_type(4))) float f32x4;

struct __align__(8) u16x4 { u16 x, y, z, w; };

typedef const void __attribute__((address_space(1))) gas_t;
typedef void __attribute__((address_space(3))) las_t;

static __device__ __forceinline__ void gload16(const void* g, void* l) {
  __builtin_amdgcn_global_load_lds((gas_t*)g, (las_t*)l, 16, 0, 0);
}

static __device__ __forceinline__ u16 f2b(float x) {
  uint32_t u = __builtin_bit_cast(uint32_t, x);
  uint32_t r = u + 0x7fffu + ((u >> 16) & 1u);
  return (u16)(r >> 16);
}
static __device__ __forceinline__ float b2lo(uint32_t u) {
  return __builtin_bit_cast(float, u << 16);
}
static __device__ __forceinline__ float b2hi(uint32_t u) {
  return __builtin_bit_cast(float, u & 0xffff0000u);
}
static __device__ __forceinline__ uint32_t pkbf16(float lo, float hi) {
  uint32_t w;
  asm("v_cvt_pk_bf16_f32 %0, %1, %2" : "=v"(w) : "v"(lo), "v"(hi));
  return w;
}
static __device__ __forceinline__ float sigf(float x) {
  return __builtin_amdgcn_rcpf(1.f + __expf(-x));
}
static __device__ __forceinline__ float tanh_(float x) {
  return 1.f - 2.f * __builtin_amdgcn_rcpf(1.f + __expf(2.f * x));
}
static __device__ __forceinline__ f32x4 MFMA(bf16x8 a, bf16x8 b, f32x4 c) {
  return __builtin_amdgcn_mfma_f32_16x16x32_bf16(a, b, c, 0, 0, 0);
}

// ---------------- pack_all: weights (blocks < 4200) + A gather (rest) ----------------
// WihP[2048][448] bf16; bias[2048] f32 = bih+bhh; WclsP[48][512] bf16;
// WhhF8: fp8 e4m3 B-fragments, long-index ((d*8+v)*64 + gj*8+kf)*64 + lane,
//   gj = gate*2+jf; byte e: Whh_d[gate*256+v*32+jf*16+(lane&15)][kf*32+(lane>>4)*8+e]
// A: [32768][448] bf16 (embed | rad x3 | pad).
__global__ __launch_bounds__(256) void pack_all(
    const float* __restrict__ Wih_f, const float* __restrict__ Wih_b,
    const float* __restrict__ Whh_f, const float* __restrict__ Whh_b,
    const float* __restrict__ bih_f, const float* __restrict__ bhh_f,
    const float* __restrict__ bih_b, const float* __restrict__ bhh_b,
    const float* __restrict__ Wcls,
    const int* __restrict__ data, const int* __restrict__ onerad,
    const float* __restrict__ embed, const float* __restrict__ rad,
    u16* __restrict__ WihP, unsigned int* __restrict__ WhhF8,
    float* __restrict__ biasP, u16* __restrict__ WclsP, u16* __restrict__ A) {
  if (blockIdx.x < 4200) {
    int idx = blockIdx.x * 256 + threadIdx.x;
    if (idx < 917504) {                       // 2*1024*448
      int d = idx / 458752;
      int rem = idx - d * 458752;
      int r = rem / 448, k = rem - r * 448;
      const float* W = d ? Wih_b : Wih_f;
      WihP[idx] = (k < 428) ? f2b(W[r * 428 + k]) : (u16)0;
    } else if (idx < 919552) {                // bias 2048
      int j = idx - 917504;
      int r = j & 1023;
      biasP[j] = (j >> 10) ? (bih_b[r] + bhh_b[r]) : (bih_f[r] + bhh_f[r]);
    } else if (idx < 944128) {                // Wcls 48*512
      int j = idx - 919552;
      int r = j >> 9, k = j & 511;
      WclsP[j] = (r < 33) ? f2b(Wcls[r * 512 + k]) : (u16)0;
    } else if (idx < 1075200) {               // WhhF8: 131072 dwords
      int q = idx - 944128;
      int eh = q & 1, li = (q >> 1) & 63, fi = (q >> 7) & 63;
      int v = (q >> 13) & 7, dd = q >> 16;
      int l16 = li & 15, g = li >> 4;
      int kf = fi & 7, gj = fi >> 3;
      int gate = gj >> 1, jf = gj & 1;
      int row = gate * 256 + v * 32 + jf * 16 + l16;
      int col = kf * 32 + g * 8 + eh * 4;
      const float* W = dd ? Whh_b : Whh_f;
      float4 f = *(const float4*)(W + (size_t)row * 256 + col);
      unsigned int r01 = __builtin_amdgcn_cvt_pk_fp8_f32(f.x, f.y, 0u, false) & 0xffffu;
      unsigned int r23 = __builtin_amdgcn_cvt_pk_fp8_f32(f.z, f.w, 0u, false) & 0xffffu;
      WhhF8[q] = r01 | (r23 << 16);
    }
  } else {
    int idx = (blockIdx.x - 4200) * 256 + threadIdx.x;   // 32768*112 total
    int m = idx / 112;
    int c = idx - m * 112;
    int k0 = c * 4;
    float4 vv;
    if (k0 < 128)      vv = *(const float4*)(embed + (size_t)data[m] * 128 + k0);
    else if (k0 < 228) vv = *(const float4*)(rad + (size_t)onerad[m] * 100 + (k0 - 128));
    else if (k0 < 328) vv = *(const float4*)(rad + (size_t)onerad[32768 + m] * 100 + (k0 - 228));
    else if (k0 < 428) vv = *(const float4*)(rad + (size_t)onerad[65536 + m] * 100 + (k0 - 328));
    else               vv = make_float4(0.f, 0.f, 0.f, 0.f);
    u16x4 o4 = { f2b(vv.x), f2b(vv.y), f2b(vv.z), f2b(vv.w) };
    *(u16x4*)(A + (size_t)m * 448 + k0) = o4;
  }
}

// ---------------- xg GEMM: X2 = jf-paired gate-major(A @ Wih^T + bias) ----------------
// X2 u16 layout per d (33554432 u16): idx = R*1024 + v*128 + l16*8 + gate*2 + jf,
// R = m*256+t; col = d*1024 + gate*256 + v*32 + jf*16 + l16.
__global__ __launch_bounds__(256) void gemm_xg(const u16* __restrict__ A,
    const u16* __restrict__ Bw, const float* __restrict__ bias,
    u16* __restrict__ X2) {
  __shared__ u16 As[4096];
  __shared__ u16 Bs[4096];
  int bid = blockIdx.x;
  int mt = bid >> 4, nt = bid & 15;
  int m0 = mt * 128, n0 = nt * 128;
  int tid = threadIdx.x;
  int w = tid >> 6, lane = tid & 63, l16 = lane & 15, g = lane >> 4;
  int wr = w >> 1, wc = w & 1;
  int srow = tid >> 2, sch = tid & 3;
  f32x4 zero4 = {0.f, 0.f, 0.f, 0.f};
  f32x4 acc[4][4];
#pragma unroll
  for (int i = 0; i < 4; ++i)
#pragma unroll
    for (int j = 0; j < 4; ++j) acc[i][j] = zero4;
  for (int kk = 0; kk < 14; ++kk) {
    int kb = kk * 32;
    gload16(A + (size_t)(m0 + srow) * 448 + kb + sch * 8, (char*)As + tid * 16);
    gload16(A + (size_t)(m0 + srow + 64) * 448 + kb + sch * 8, (char*)As + 4096 + tid * 16);
    gload16(Bw + (size_t)(n0 + srow) * 448 + kb + sch * 8, (char*)Bs + tid * 16);
    gload16(Bw + (size_t)(n0 + srow + 64) * 448 + kb + sch * 8, (char*)Bs + 4096 + tid * 16);
    __syncthreads();
    bf16x8 af[4], bfr[4];
#pragma unroll
    for (int i = 0; i < 4; ++i) {
      af[i]  = *(const bf16x8*)((const char*)As + (wr * 64 + i * 16 + l16) * 64 + g * 16);
      bfr[i] = *(const bf16x8*)((const char*)Bs + (wc * 64 + i * 16 + l16) * 64 + g * 16);
    }
#pragma unroll
    for (int i = 0; i < 4; ++i)
#pragma unroll
      for (int j = 0; j < 4; ++j)
        acc[i][j] = MFMA(af[i], bfr[j], acc[i][j]);
    __syncthreads();
  }
  float bv[4];
#pragma unroll
  for (int j = 0; j < 4; ++j) bv[j] = bias[n0 + wc * 64 + j * 16 + l16];
  int dd = n0 >> 10;
#pragma unroll
  for (int i = 0; i < 4; ++i)
#pragma unroll
    for (int jp = 0; jp < 2; ++jp) {
      int j0 = jp * 2;
      int c = (n0 + wc * 64 + j0 * 16 + l16) & 1023;   // jf=0 member
      int gate = c >> 8, vv = (c >> 5) & 7, lc = c & 15;
      size_t base = (size_t)dd * 33554432 + (size_t)vv * 128 + lc * 8 + gate * 2;
#pragma unroll
      for (int r = 0; r < 4; ++r) {
        int row = m0 + wr * 64 + i * 16 + g * 4 + r;
        *(unsigned int*)(X2 + base + (size_t)row * 1024) =
            pkbf16(acc[i][j0][r] + bv[j0], acc[i][j0 + 1][r] + bv[j0 + 1]);
      }
    }
}

// ---------------- LSTM recurrence: 32 blocks, one 8-row chunk each ----------------
// r14 structure (proven, 507us): Whh pinned (64 longs/lane). MFMA M=16 tile,
// rows 8-15 zero. Lane-redistributed activations; uint4 px.
#define PIN(n) long q##n; \
  asm volatile("global_load_dwordx2 %0, %1, off" : "=v"(q##n) : "v"(wbase + (n) * 512));
#define MMG(acc, gj, bn) \
  acc[gj] = __builtin_amdgcn_mfma_f32_16x16x32_fp8_fp8(a, bn, acc[gj], 0, 0, 0);
#define KSTEP(acc, fr, kf, B0, B1, B2, B3, B4, B5, B6, B7) { \
  long a = fr[(kf) * 64 + lane]; \
  MMG(acc, 0, B0) MMG(acc, 1, B1) MMG(acc, 2, B2) MMG(acc, 3, B3) \
  MMG(acc, 4, B4) MMG(acc, 5, B5) MMG(acc, 6, B6) MMG(acc, 7, B7) }
#define MFMA_PHASE(acc, hf) { \
  const long* fr = (const long*)(hf); \
  acc[0] = zero4; acc[1] = zero4; acc[2] = zero4; acc[3] = zero4; \
  acc[4] = zero4; acc[5] = zero4; acc[6] = zero4; acc[7] = zero4; \
  KSTEP(acc, fr, 0, q0, q8,  q16, q24, q32, q40, q48, q56) \
  KSTEP(acc, fr, 1, q1, q9,  q17, q25, q33, q41, q49, q57) \
  KSTEP(acc, fr, 2, q2, q10, q18, q26, q34, q42, q50, q58) \
  KSTEP(acc, fr, 3, q3, q11, q19, q27, q35, q43, q51, q59) \
  KSTEP(acc, fr, 4, q4, q12, q20, q28, q36, q44, q52, q60) \
  KSTEP(acc, fr, 5, q5, q13, q21, q29, q37, q45, q53, q61) \
  KSTEP(acc, fr, 6, q6, q14, q22, q30, q38, q46, q54, q62) \
  KSTEP(acc, fr, 7, q7, q15, q23, q31, q39, q47, q55, q63) }
#define TRANS(acc, cst, hf, sb, px) { \
  _Pragma("unroll") \
  for (int r = 0; r < 4; ++r) { \
    float o0 = __shfl_xor(acc[1][r], 32); \
    float o1 = __shfl_xor(acc[3][r], 32); \
    float o2 = __shfl_xor(acc[5][r], 32); \
    float o3 = __shfl_xor(acc[7][r], 32); \
    float iv = lo32 ? (acc[0][r] + b2lo(px[r].x)) : (o0 + b2hi(px[r].x)); \
    float fv = lo32 ? (acc[2][r] + b2lo(px[r].y)) : (o1 + b2hi(px[r].y)); \
    float gv = lo32 ? (acc[4][r] + b2lo(px[r].z)) : (o2 + b2hi(px[r].z)); \
    float ov = lo32 ? (acc[6][r] + b2lo(px[r].w)) : (o3 + b2hi(px[r].w)); \
    float cn = sigf(fv) * cst[r] + sigf(iv) * tanh_(gv); \
    cst[r] = cn; \
    float hv = sigf(ov) * tanh_(cn); \
    ((unsigned char*)(hf))[fwoff + r * 8] = \
        (unsigned char)__builtin_amdgcn_cvt_pk_fp8_f32(hv, hv, 0u, false); \
    *(u16*)(sb[r] + voff_st) = f2b(hv); \
  } }
#define BUMP4(p, s) { p[0] += s; p[1] += s; p[2] += s; p[3] += s; }
#define LOADPX(px, pb) { \
  px[0] = *(const uint4*)(pb[0] + voff_px); \
  px[1] = *(const uint4*)(pb[1] + voff_px); \
  px[2] = *(const uint4*)(pb[2] + voff_px); \
  px[3] = *(const uint4*)(pb[3] + voff_px); }
#define FENCE { __builtin_amdgcn_sched_barrier(0); \
  asm volatile("s_waitcnt lgkmcnt(0)"); \
  __builtin_amdgcn_s_barrier(); \
  __builtin_amdgcn_sched_barrier(0); }

__global__ __launch_bounds__(512, 1) void lstm_recur(const u16* __restrict__ xg,
    const unsigned char* __restrict__ WhhF8, u16* __restrict__ outh) {
  __shared__ unsigned char hfA[2][4096];
  int blk = blockIdx.x;
  int d = blk >> 4, c8 = blk & 15;
  int rowA0 = c8 * 8;
  int tid = threadIdx.x;
  int v = tid >> 6, lane = tid & 63, l16 = lane & 15, g = lane >> 4;
  int jfL = g >> 1, gl = g & 1;
  bool lo32 = (lane < 32);

  const char* wbase = (const char*)WhhF8 + ((size_t)(d * 8 + v) * 4096 + lane) * 8;
  PIN(0)  PIN(1)  PIN(2)  PIN(3)  PIN(4)  PIN(5)  PIN(6)  PIN(7)
  PIN(8)  PIN(9)  PIN(10) PIN(11) PIN(12) PIN(13) PIN(14) PIN(15)
  PIN(16) PIN(17) PIN(18) PIN(19) PIN(20) PIN(21) PIN(22) PIN(23)
  PIN(24) PIN(25) PIN(26) PIN(27) PIN(28) PIN(29) PIN(30) PIN(31)
  PIN(32) PIN(33) PIN(34) PIN(35) PIN(36) PIN(37) PIN(38) PIN(39)
  PIN(40) PIN(41) PIN(42) PIN(43) PIN(44) PIN(45) PIN(46) PIN(47)
  PIN(48) PIN(49) PIN(50) PIN(51) PIN(52) PIN(53) PIN(54) PIN(55)
  PIN(56) PIN(57) PIN(58) PIN(59) PIN(60) PIN(61) PIN(62) PIN(63)

  for (int i = tid; i < 2048; i += 512) ((int*)hfA)[i] = 0;

  int t0 = d ? 255 : 0;
  int tpx = d ? -2048 : 2048;    // bytes per t-step in X2 (1024 u16/row-step)
  int tob = d ? -1024 : 1024;    // bytes per t-step in outh (512 u16)

  const char* X2b = (const char*)xg + (size_t)d * 67108864;
  char* outhb = (char*)outh;
  const char* pbA[4];
  char* sbA[4];
#pragma unroll
  for (int r = 0; r < 4; ++r) {
    pbA[r] = X2b + ((size_t)(rowA0 + gl * 4 + r) * 256 + t0) * 2048;
    sbA[r] = outhb + (((size_t)(rowA0 + gl * 4 + r) * 256 + t0) * 512 + d * 256) * 2;
  }
  int voff_px = v * 256 + l16 * 16;
  int voff_st = (v * 32 + jfL * 16 + l16) * 2;
  int fwoff = (v * 64 + jfL * 32 + (l16 >> 3) * 16 + gl * 4) * 8 + (l16 & 7);

  uint4 pxA[4];
  LOADPX(pxA, pbA);

  asm volatile("s_waitcnt vmcnt(0)" ::: "memory");
  __builtin_amdgcn_sched_barrier(0);

  f32x4 zero4 = {0.f, 0.f, 0.f, 0.f};
  f32x4 cstA = zero4;
  f32x4 accA[8];
  __syncthreads();

#pragma unroll 1
  for (int tt = 0; tt < 256; ++tt) {
    int p = tt & 1;
    MFMA_PHASE(accA, &hfA[p][0]);
    {
      unsigned char* hf = &hfA[p ^ 1][0];
      TRANS(accA, cstA, hf, sbA, pxA);
    }
    BUMP4(sbA, tob); BUMP4(pbA, tpx);
    LOADPX(pxA, pbA);
    FENCE;
  }
}

// ---------------- emission: [32768][33] f32 = outh @ Wcls^T + bcls ----------------
__global__ __launch_bounds__(256) void emis_k(const u16* __restrict__ outh,
    const u16* __restrict__ WclsP, const float* __restrict__ bcls,
    float* __restrict__ emiB) {
  int tid = threadIdx.x;
  int w = tid >> 6, lane = tid & 63, l16 = lane & 15, g = lane >> 4;
  int mrow = blockIdx.x * 64 + w * 16;
  f32x4 zero4 = {0.f, 0.f, 0.f, 0.f};
  f32x4 acc[3] = {zero4, zero4, zero4};
#pragma unroll
  for (int kf = 0; kf < 16; ++kf) {
    bf16x8 a = *(const bf16x8*)(outh + (size_t)(mrow + l16) * 512 + kf * 32 + g * 8);
#pragma unroll
    for (int nf = 0; nf < 3; ++nf) {
      bf16x8 bb = *(const bf16x8*)(WclsP + (size_t)(nf * 16 + l16) * 512 + kf * 32 + g * 8);
      acc[nf] = MFMA(a, bb, acc[nf]);
    }
  }
#pragma unroll
  for (int nf = 0; nf < 3; ++nf) {
    int c = nf * 16 + l16;
    if (c < 33) {
      float bc = bcls[c];
#pragma unroll
      for (int r = 0; r < 4; ++r)
        emiB[(size_t)(mrow + g * 4 + r) * 33 + c] = acc[nf][r] + bc;
    }
  }
}

// ---------------- CRF forward + golden, fused; emissions LDS-resident ----------------
// 128 blocks x 64 thr. E[256][33] (33.8KB) + Ts (4.3KB) staged once.
// part[b] = all_path_end - golden.
__global__ __launch_bounds__(64) void crf2_k(const int* __restrict__ tag,
    const float* __restrict__ emiB, const float* __restrict__ T,
    float* __restrict__ part) {
  int b = blockIdx.x;
  int lane = threadIdx.x;
  __shared__ float Ts[1089];
  __shared__ float E[8448];
  __shared__ float sc[33];
  for (int i = lane; i < 1089; i += 64) Ts[i] = T[i];
  {
    const float* eb = emiB + (size_t)b * 8448;
    for (int i = lane; i < 8448; i += 64) E[i] = eb[i];
  }
  int cnt = 0;
  for (int i = lane; i < 256; i += 64) cnt += (tag[b * 256 + i] != 0) ? 1 : 0;
#pragma unroll
  for (int o = 1; o < 64; o <<= 1) cnt += __shfl_xor(cnt, o);
  int len = cnt;
  __syncthreads();
  // golden path score (lane-strided over timesteps)
  float gval = 0.f;
  for (int l = lane; l < 256; l += 64) {
    int tg = tag[b * 256 + l];
    if (tg != 0) {
      int prev = (l == 0) ? 31 : tag[b * 256 + l - 1];
      gval += E[l * 33 + tg] + Ts[prev * 33 + tg];
    }
  }
#pragma unroll
  for (int o = 32; o > 0; o >>= 1) gval += __shfl_down(gval, o);
  // forward scan
  int c = lane;
  float tcol[33];
  if (c < 33) {
#pragma unroll
    for (int p = 0; p < 33; ++p) tcol[p] = Ts[p * 33 + c];
    sc[c] = E[c] + tcol[31];   // START=31
  }
  __syncthreads();
#pragma unroll 1
  for (int t = 1; t < len; ++t) {
    float nv = 0.f;
    if (c < 33) {
      float ec = E[t * 33 + c];
      float vb[33];
      float m0 = -3.0e38f, m1 = -3.0e38f, m2 = -3.0e38f, m3 = -3.0e38f;
#pragma unroll
      for (int p = 0; p < 32; p += 4) {
        vb[p]     = sc[p]     + tcol[p];     m0 = fmaxf(m0, vb[p]);
        vb[p + 1] = sc[p + 1] + tcol[p + 1]; m1 = fmaxf(m1, vb[p + 1]);
        vb[p + 2] = sc[p + 2] + tcol[p + 2]; m2 = fmaxf(m2, vb[p + 2]);
        vb[p + 3] = sc[p + 3] + tcol[p + 3]; m3 = fmaxf(m3, vb[p + 3]);
      }
      vb[32] = sc[32] + tcol[32];
      float mx = fmaxf(fmaxf(fmaxf(m0, m1), fmaxf(m2, m3)), vb[32]);
      float s0 = 0.f, s1 = 0.f, s2 = 0.f, s3 = 0.f;
#pragma unroll
      for (int p = 0; p < 32; p += 4) {
        s0 += __expf(vb[p] - mx);     s1 += __expf(vb[p + 1] - mx);
        s2 += __expf(vb[p + 2] - mx); s3 += __expf(vb[p + 3] - mx);
      }
      s0 += __expf(vb[32] - mx);
      nv = ec + mx + __logf((s0 + s1) + (s2 + s3));
    }
    __syncthreads();
    if (c < 33) sc[c] = nv;
    __syncthreads();
  }
  if (lane == 0) part[b] = sc[32] - gval;   // END=32
}

// ---------------- finalize: loss = sum(part) / 128 ----------------
__global__ __launch_bounds__(64) void fin_k(const float* __restrict__ part,
    float* __restrict__ out) {
  int l = threadIdx.x;
  float v = part[l] + part[l + 64];
#pragma unroll
  for (int o = 32; o > 0; o >>= 1) v += __shfl_down(v, o);
  if (l == 0) out[0] = v / 128.f;
}

extern "C" void kernel_launch(void* const* d_in, const int* in_sizes, int n_in,
                              void* d_out, int out_size, void* d_ws, size_t ws_size,
                              hipStream_t stream) {
  const int*   batch_data   = (const int*)d_in[0];
  const int*   batch_onerad = (const int*)d_in[1];
  const int*   batch_tag    = (const int*)d_in[2];
  const float* embed        = (const float*)d_in[3];
  const float* rad_embed    = (const float*)d_in[4];
  const float* Wih_f = (const float*)d_in[5];
  const float* Whh_f = (const float*)d_in[6];
  const float* bih_f = (const float*)d_in[7];
  const float* bhh_f = (const float*)d_in[8];
  const float* Wih_b = (const float*)d_in[9];
  const float* Whh_b = (const float*)d_in[10];
  const float* bih_b = (const float*)d_in[11];
  const float* bhh_b = (const float*)d_in[12];
  const float* Wcls  = (const float*)d_in[13];
  const float* bcls  = (const float*)d_in[14];
  const float* trans = (const float*)d_in[15];

  // workspace layout (~203.9 MB)
  char* ws = (char*)d_ws;
  u16*   Apack = (u16*)  (ws + 0);            // 29360128
  u16*   X2    = (u16*)  (ws + 29360128);     // 134217728 (jf-paired xg)
  u16*   WihP  = (u16*)  (ws + 163577856);    // 1835008
  unsigned int* WhhF8 = (unsigned int*)(ws + 165412864); // 524288
  float* biasP = (float*)(ws + 165937152);    // 8192
  u16*   WclsP = (u16*)  (ws + 165945344);    // 49152
  u16*   outh  = (u16*)  (ws + 165994496);    // 33554432
  float* emiB  = (float*)(ws + 199548928);    // 4325376
  float* part  = (float*)(ws + 203874304);    // 512

  pack_all<<<18536, 256, 0, stream>>>(Wih_f, Wih_b, Whh_f, Whh_b, bih_f, bhh_f,
                                      bih_b, bhh_b, Wcls, batch_data, batch_onerad,
                                      embed, rad_embed, WihP, WhhF8, biasP, WclsP, Apack);
  gemm_xg<<<4096, 256, 0, stream>>>(Apack, WihP, biasP, X2);
  lstm_recur<<<32, 512, 0, stream>>>(X2, (const unsigned char*)WhhF8, outh);
  emis_k<<<512, 256, 0, stream>>>(outh, WclsP, bcls, emiB);
  crf2_k<<<128, 64, 0, stream>>>(batch_tag, emiB, trans, part);
  fin_k<<<1, 64, 0, stream>>>(part, (float*)d_out);
}

// Round 16
// 702.466 us; speedup vs baseline: 1.1791x; 1.1744x over previous
//
#include <hip/hip_runtime.h>
#include <hip/hip_bf16.h>
#include <stdint.h>

// LSTM-CRF forward loss. B=128 L=256 V=6000 E=128 RV=300 RD=100 H=256 C=33
// DIN=428 (pad to 448). Pipeline:
//   pack_all (weights+A) -> gemm_xg (pair-contiguous X2, full-line stores)
//   -> lstm_recur (32 wg x 512 thr; Whh pinned; 4xu32 px)  [r14 core]
//   -> emis_k -> crf2_k (LDS emissions + golden fused) -> fin_k

typedef unsigned short u16;
typedef __attribute__((ext_vector_type(8))) __bf16 bf16x8;
typedef __attribute__((ext_vector_type(4))) float f32x4;

struct __align__(8) u16x4 { u16 x, y, z, w; };

typedef const void __attribute__((address_space(1))) gas_t;
typedef void __attribute__((address_space(3))) las_t;

static __device__ __forceinline__ void gload16(const void* g, void* l) {
  __builtin_amdgcn_global_load_lds((gas_t*)g, (las_t*)l, 16, 0, 0);
}

static __device__ __forceinline__ u16 f2b(float x) {
  uint32_t u = __builtin_bit_cast(uint32_t, x);
  uint32_t r = u + 0x7fffu + ((u >> 16) & 1u);
  return (u16)(r >> 16);
}
static __device__ __forceinline__ float b2lo(uint32_t u) {
  return __builtin_bit_cast(float, u << 16);
}
static __device__ __forceinline__ float b2hi(uint32_t u) {
  return __builtin_bit_cast(float, u & 0xffff0000u);
}
static __device__ __forceinline__ uint32_t pkbf16(float lo, float hi) {
  uint32_t w;
  asm("v_cvt_pk_bf16_f32 %0, %1, %2" : "=v"(w) : "v"(lo), "v"(hi));
  return w;
}
static __device__ __forceinline__ float sigf(float x) {
  return __builtin_amdgcn_rcpf(1.f + __expf(-x));
}
static __device__ __forceinline__ float tanh_(float x) {
  return 1.f - 2.f * __builtin_amdgcn_rcpf(1.f + __expf(2.f * x));
}
static __device__ __forceinline__ f32x4 MFMA(bf16x8 a, bf16x8 b, f32x4 c) {
  return __builtin_amdgcn_mfma_f32_16x16x32_bf16(a, b, c, 0, 0, 0);
}

// ---------------- pack_all: weights (blocks < 4200) + A gather (rest) ----------------
__global__ __launch_bounds__(256) void pack_all(
    const float* __restrict__ Wih_f, const float* __restrict__ Wih_b,
    const float* __restrict__ Whh_f, const float* __restrict__ Whh_b,
    const float* __restrict__ bih_f, const float* __restrict__ bhh_f,
    const float* __restrict__ bih_b, const float* __restrict__ bhh_b,
    const float* __restrict__ Wcls,
    const int* __restrict__ data, const int* __restrict__ onerad,
    const float* __restrict__ embed, const float* __restrict__ rad,
    u16* __restrict__ WihP, unsigned int* __restrict__ WhhF8,
    float* __restrict__ biasP, u16* __restrict__ WclsP, u16* __restrict__ A) {
  if (blockIdx.x < 4200) {
    int idx = blockIdx.x * 256 + threadIdx.x;
    if (idx < 917504) {                       // 2*1024*448
      int d = idx / 458752;
      int rem = idx - d * 458752;
      int r = rem / 448, k = rem - r * 448;
      const float* W = d ? Wih_b : Wih_f;
      WihP[idx] = (k < 428) ? f2b(W[r * 428 + k]) : (u16)0;
    } else if (idx < 919552) {                // bias 2048
      int j = idx - 917504;
      int r = j & 1023;
      biasP[j] = (j >> 10) ? (bih_b[r] + bhh_b[r]) : (bih_f[r] + bhh_f[r]);
    } else if (idx < 944128) {                // Wcls 48*512
      int j = idx - 919552;
      int r = j >> 9, k = j & 511;
      WclsP[j] = (r < 33) ? f2b(Wcls[r * 512 + k]) : (u16)0;
    } else if (idx < 1075200) {               // WhhF8: 131072 dwords
      int q = idx - 944128;
      int eh = q & 1, li = (q >> 1) & 63, fi = (q >> 7) & 63;
      int v = (q >> 13) & 7, dd = q >> 16;
      int l16 = li & 15, g = li >> 4;
      int kf = fi & 7, gj = fi >> 3;
      int gate = gj >> 1, jf = gj & 1;
      int row = gate * 256 + v * 32 + jf * 16 + l16;
      int col = kf * 32 + g * 8 + eh * 4;
      const float* W = dd ? Whh_b : Whh_f;
      float4 f = *(const float4*)(W + (size_t)row * 256 + col);
      unsigned int r01 = __builtin_amdgcn_cvt_pk_fp8_f32(f.x, f.y, 0u, false) & 0xffffu;
      unsigned int r23 = __builtin_amdgcn_cvt_pk_fp8_f32(f.z, f.w, 0u, false) & 0xffffu;
      WhhF8[q] = r01 | (r23 << 16);
    }
  } else {
    int idx = (blockIdx.x - 4200) * 256 + threadIdx.x;   // 32768*112 total
    int m = idx / 112;
    int c = idx - m * 112;
    int k0 = c * 4;
    float4 vv;
    if (k0 < 128)      vv = *(const float4*)(embed + (size_t)data[m] * 128 + k0);
    else if (k0 < 228) vv = *(const float4*)(rad + (size_t)onerad[m] * 100 + (k0 - 128));
    else if (k0 < 328) vv = *(const float4*)(rad + (size_t)onerad[32768 + m] * 100 + (k0 - 228));
    else if (k0 < 428) vv = *(const float4*)(rad + (size_t)onerad[65536 + m] * 100 + (k0 - 328));
    else               vv = make_float4(0.f, 0.f, 0.f, 0.f);
    u16x4 o4 = { f2b(vv.x), f2b(vv.y), f2b(vv.z), f2b(vv.w) };
    *(u16x4*)(A + (size_t)m * 448 + k0) = o4;
  }
}

// ---------------- xg GEMM: X2 = pair-contiguous(A @ Wih^T + bias) ----------------
// X2 u16 layout per d (33554432 u16): idx = R*1024 + gate*256 + v*32 + l16*2 + jf,
// R = m*256+t; orig col = d*1024 + gate*256 + v*32 + jf*16 + l16.
// Epilogue: paired b32 stores; lanes l16 -> 64 contiguous bytes (full lines).
__global__ __launch_bounds__(256) void gemm_xg(const u16* __restrict__ A,
    const u16* __restrict__ Bw, const float* __restrict__ bias,
    u16* __restrict__ X2) {
  __shared__ u16 As[4096];
  __shared__ u16 Bs[4096];
  int bid = blockIdx.x;
  int mt = bid >> 4, nt = bid & 15;
  int m0 = mt * 128, n0 = nt * 128;
  int tid = threadIdx.x;
  int w = tid >> 6, lane = tid & 63, l16 = lane & 15, g = lane >> 4;
  int wr = w >> 1, wc = w & 1;
  int srow = tid >> 2, sch = tid & 3;
  f32x4 zero4 = {0.f, 0.f, 0.f, 0.f};
  f32x4 acc[4][4];
#pragma unroll
  for (int i = 0; i < 4; ++i)
#pragma unroll
    for (int j = 0; j < 4; ++j) acc[i][j] = zero4;
  for (int kk = 0; kk < 14; ++kk) {
    int kb = kk * 32;
    gload16(A + (size_t)(m0 + srow) * 448 + kb + sch * 8, (char*)As + tid * 16);
    gload16(A + (size_t)(m0 + srow + 64) * 448 + kb + sch * 8, (char*)As + 4096 + tid * 16);
    gload16(Bw + (size_t)(n0 + srow) * 448 + kb + sch * 8, (char*)Bs + tid * 16);
    gload16(Bw + (size_t)(n0 + srow + 64) * 448 + kb + sch * 8, (char*)Bs + 4096 + tid * 16);
    __syncthreads();
    bf16x8 af[4], bfr[4];
#pragma unroll
    for (int i = 0; i < 4; ++i) {
      af[i]  = *(const bf16x8*)((const char*)As + (wr * 64 + i * 16 + l16) * 64 + g * 16);
      bfr[i] = *(const bf16x8*)((const char*)Bs + (wc * 64 + i * 16 + l16) * 64 + g * 16);
    }
#pragma unroll
    for (int i = 0; i < 4; ++i)
#pragma unroll
      for (int j = 0; j < 4; ++j)
        acc[i][j] = MFMA(af[i], bfr[j], acc[i][j]);
    __syncthreads();
  }
  float bv[4];
#pragma unroll
  for (int j = 0; j < 4; ++j) bv[j] = bias[n0 + wc * 64 + j * 16 + l16];
  int dd = n0 >> 10;
#pragma unroll
  for (int i = 0; i < 4; ++i)
#pragma unroll
    for (int jp = 0; jp < 2; ++jp) {
      int j0 = jp * 2;
      int c = (n0 + wc * 64 + j0 * 16 + l16) & 1023;   // jf=0 member
      int gate = c >> 8, vv = (c >> 5) & 7, lc = c & 15;
      size_t base = (size_t)dd * 33554432 + (size_t)gate * 256 + vv * 32 + lc * 2;
#pragma unroll
      for (int r = 0; r < 4; ++r) {
        int row = m0 + wr * 64 + i * 16 + g * 4 + r;
        *(unsigned int*)(X2 + base + (size_t)row * 1024) =
            pkbf16(acc[i][j0][r] + bv[j0], acc[i][j0 + 1][r] + bv[j0 + 1]);
      }
    }
}

// ---------------- LSTM recurrence: 32 blocks, one 8-row chunk each ----------------
// r14 structure: Whh pinned (64 longs/lane). MFMA M=16 tile, rows 8-15 zero.
// Lane-redistributed activations; px = 4 x u32 (one jf-pair per gate).
#define PIN(n) long q##n; \
  asm volatile("global_load_dwordx2 %0, %1, off" : "=v"(q##n) : "v"(wbase + (n) * 512));
#define MMG(acc, gj, bn) \
  acc[gj] = __builtin_amdgcn_mfma_f32_16x16x32_fp8_fp8(a, bn, acc[gj], 0, 0, 0);
#define KSTEP(acc, fr, kf, B0, B1, B2, B3, B4, B5, B6, B7) { \
  long a = fr[(kf) * 64 + lane]; \
  MMG(acc, 0, B0) MMG(acc, 1, B1) MMG(acc, 2, B2) MMG(acc, 3, B3) \
  MMG(acc, 4, B4) MMG(acc, 5, B5) MMG(acc, 6, B6) MMG(acc, 7, B7) }
#define MFMA_PHASE(acc, hf) { \
  const long* fr = (const long*)(hf); \
  acc[0] = zero4; acc[1] = zero4; acc[2] = zero4; acc[3] = zero4; \
  acc[4] = zero4; acc[5] = zero4; acc[6] = zero4; acc[7] = zero4; \
  KSTEP(acc, fr, 0, q0, q8,  q16, q24, q32, q40, q48, q56) \
  KSTEP(acc, fr, 1, q1, q9,  q17, q25, q33, q41, q49, q57) \
  KSTEP(acc, fr, 2, q2, q10, q18, q26, q34, q42, q50, q58) \
  KSTEP(acc, fr, 3, q3, q11, q19, q27, q35, q43, q51, q59) \
  KSTEP(acc, fr, 4, q4, q12, q20, q28, q36, q44, q52, q60) \
  KSTEP(acc, fr, 5, q5, q13, q21, q29, q37, q45, q53, q61) \
  KSTEP(acc, fr, 6, q6, q14, q22, q30, q38, q46, q54, q62) \
  KSTEP(acc, fr, 7, q7, q15, q23, q31, q39, q47, q55, q63) }
#define TRANS(acc, cst, hf, sb, px) { \
  _Pragma("unroll") \
  for (int r = 0; r < 4; ++r) { \
    float o0 = __shfl_xor(acc[1][r], 32); \
    float o1 = __shfl_xor(acc[3][r], 32); \
    float o2 = __shfl_xor(acc[5][r], 32); \
    float o3 = __shfl_xor(acc[7][r], 32); \
    float iv = lo32 ? (acc[0][r] + b2lo(px[r].x)) : (o0 + b2hi(px[r].x)); \
    float fv = lo32 ? (acc[2][r] + b2lo(px[r].y)) : (o1 + b2hi(px[r].y)); \
    float gv = lo32 ? (acc[4][r] + b2lo(px[r].z)) : (o2 + b2hi(px[r].z)); \
    float ov = lo32 ? (acc[6][r] + b2lo(px[r].w)) : (o3 + b2hi(px[r].w)); \
    float cn = sigf(fv) * cst[r] + sigf(iv) * tanh_(gv); \
    cst[r] = cn; \
    float hv = sigf(ov) * tanh_(cn); \
    ((unsigned char*)(hf))[fwoff + r * 8] = \
        (unsigned char)__builtin_amdgcn_cvt_pk_fp8_f32(hv, hv, 0u, false); \
    *(u16*)(sb[r] + voff_st) = f2b(hv); \
  } }
#define BUMP4(p, s) { p[0] += s; p[1] += s; p[2] += s; p[3] += s; }
#define LOADPX(px, pb) { \
  px[0].x = *(const unsigned int*)(pb[0] + voff_px); \
  px[0].y = *(const unsigned int*)(pb[0] + voff_px + 512); \
  px[0].z = *(const unsigned int*)(pb[0] + voff_px + 1024); \
  px[0].w = *(const unsigned int*)(pb[0] + voff_px + 1536); \
  px[1].x = *(const unsigned int*)(pb[1] + voff_px); \
  px[1].y = *(const unsigned int*)(pb[1] + voff_px + 512); \
  px[1].z = *(const unsigned int*)(pb[1] + voff_px + 1024); \
  px[1].w = *(const unsigned int*)(pb[1] + voff_px + 1536); \
  px[2].x = *(const unsigned int*)(pb[2] + voff_px); \
  px[2].y = *(const unsigned int*)(pb[2] + voff_px + 512); \
  px[2].z = *(const unsigned int*)(pb[2] + voff_px + 1024); \
  px[2].w = *(const unsigned int*)(pb[2] + voff_px + 1536); \
  px[3].x = *(const unsigned int*)(pb[3] + voff_px); \
  px[3].y = *(const unsigned int*)(pb[3] + voff_px + 512); \
  px[3].z = *(const unsigned int*)(pb[3] + voff_px + 1024); \
  px[3].w = *(const unsigned int*)(pb[3] + voff_px + 1536); }
#define FENCE { __builtin_amdgcn_sched_barrier(0); \
  asm volatile("s_waitcnt lgkmcnt(0)"); \
  __builtin_amdgcn_s_barrier(); \
  __builtin_amdgcn_sched_barrier(0); }

__global__ __launch_bounds__(512, 1) void lstm_recur(const u16* __restrict__ xg,
    const unsigned char* __restrict__ WhhF8, u16* __restrict__ outh) {
  __shared__ unsigned char hfA[2][4096];
  int blk = blockIdx.x;
  int d = blk >> 4, c8 = blk & 15;
  int rowA0 = c8 * 8;
  int tid = threadIdx.x;
  int v = tid >> 6, lane = tid & 63, l16 = lane & 15, g = lane >> 4;
  int jfL = g >> 1, gl = g & 1;
  bool lo32 = (lane < 32);

  const char* wbase = (const char*)WhhF8 + ((size_t)(d * 8 + v) * 4096 + lane) * 8;
  PIN(0)  PIN(1)  PIN(2)  PIN(3)  PIN(4)  PIN(5)  PIN(6)  PIN(7)
  PIN(8)  PIN(9)  PIN(10) PIN(11) PIN(12) PIN(13) PIN(14) PIN(15)
  PIN(16) PIN(17) PIN(18) PIN(19) PIN(20) PIN(21) PIN(22) PIN(23)
  PIN(24) PIN(25) PIN(26) PIN(27) PIN(28) PIN(29) PIN(30) PIN(31)
  PIN(32) PIN(33) PIN(34) PIN(35) PIN(36) PIN(37) PIN(38) PIN(39)
  PIN(40) PIN(41) PIN(42) PIN(43) PIN(44) PIN(45) PIN(46) PIN(47)
  PIN(48) PIN(49) PIN(50) PIN(51) PIN(52) PIN(53) PIN(54) PIN(55)
  PIN(56) PIN(57) PIN(58) PIN(59) PIN(60) PIN(61) PIN(62) PIN(63)

  for (int i = tid; i < 2048; i += 512) ((int*)hfA)[i] = 0;

  int t0 = d ? 255 : 0;
  int tpx = d ? -2048 : 2048;    // bytes per t-step in X2 (1024 u16/row-step)
  int tob = d ? -1024 : 1024;    // bytes per t-step in outh (512 u16)

  const char* X2b = (const char*)xg + (size_t)d * 67108864;
  char* outhb = (char*)outh;
  const char* pbA[4];
  char* sbA[4];
#pragma unroll
  for (int r = 0; r < 4; ++r) {
    pbA[r] = X2b + ((size_t)(rowA0 + gl * 4 + r) * 256 + t0) * 2048;
    sbA[r] = outhb + (((size_t)(rowA0 + gl * 4 + r) * 256 + t0) * 512 + d * 256) * 2;
  }
  int voff_px = v * 64 + l16 * 4;                 // bytes; gate stride 512 B
  int voff_st = (v * 32 + jfL * 16 + l16) * 2;
  int fwoff = (v * 64 + jfL * 32 + (l16 >> 3) * 16 + gl * 4) * 8 + (l16 & 7);

  uint4 pxA[4];
  LOADPX(pxA, pbA);

  asm volatile("s_waitcnt vmcnt(0)" ::: "memory");
  __builtin_amdgcn_sched_barrier(0);

  f32x4 zero4 = {0.f, 0.f, 0.f, 0.f};
  f32x4 cstA = zero4;
  f32x4 accA[8];
  __syncthreads();

#pragma unroll 1
  for (int tt = 0; tt < 256; ++tt) {
    int p = tt & 1;
    MFMA_PHASE(accA, &hfA[p][0]);
    {
      unsigned char* hf = &hfA[p ^ 1][0];
      TRANS(accA, cstA, hf, sbA, pxA);
    }
    BUMP4(sbA, tob); BUMP4(pbA, tpx);
    LOADPX(pxA, pbA);
    FENCE;
  }
}

// ---------------- emission: [32768][33] f32 = outh @ Wcls^T + bcls ----------------
__global__ __launch_bounds__(256) void emis_k(const u16* __restrict__ outh,
    const u16* __restrict__ WclsP, const float* __restrict__ bcls,
    float* __restrict__ emiB) {
  int tid = threadIdx.x;
  int w = tid >> 6, lane = tid & 63, l16 = lane & 15, g = lane >> 4;
  int mrow = blockIdx.x * 64 + w * 16;
  f32x4 zero4 = {0.f, 0.f, 0.f, 0.f};
  f32x4 acc[3] = {zero4, zero4, zero4};
#pragma unroll
  for (int kf = 0; kf < 16; ++kf) {
    bf16x8 a = *(const bf16x8*)(outh + (size_t)(mrow + l16) * 512 + kf * 32 + g * 8);
#pragma unroll
    for (int nf = 0; nf < 3; ++nf) {
      bf16x8 bb = *(const bf16x8*)(WclsP + (size_t)(nf * 16 + l16) * 512 + kf * 32 + g * 8);
      acc[nf] = MFMA(a, bb, acc[nf]);
    }
  }
#pragma unroll
  for (int nf = 0; nf < 3; ++nf) {
    int c = nf * 16 + l16;
    if (c < 33) {
      float bc = bcls[c];
#pragma unroll
      for (int r = 0; r < 4; ++r)
        emiB[(size_t)(mrow + g * 4 + r) * 33 + c] = acc[nf][r] + bc;
    }
  }
}

// ---------------- CRF forward + golden, fused; emissions LDS-resident ----------------
__global__ __launch_bounds__(64) void crf2_k(const int* __restrict__ tag,
    const float* __restrict__ emiB, const float* __restrict__ T,
    float* __restrict__ part) {
  int b = blockIdx.x;
  int lane = threadIdx.x;
  __shared__ float Ts[1089];
  __shared__ float E[8448];
  __shared__ float sc[33];
  for (int i = lane; i < 1089; i += 64) Ts[i] = T[i];
  {
    const float* eb = emiB + (size_t)b * 8448;
    for (int i = lane; i < 8448; i += 64) E[i] = eb[i];
  }
  int cnt = 0;
  for (int i = lane; i < 256; i += 64) cnt += (tag[b * 256 + i] != 0) ? 1 : 0;
#pragma unroll
  for (int o = 1; o < 64; o <<= 1) cnt += __shfl_xor(cnt, o);
  int len = cnt;
  __syncthreads();
  float gval = 0.f;
  for (int l = lane; l < 256; l += 64) {
    int tg = tag[b * 256 + l];
    if (tg != 0) {
      int prev = (l == 0) ? 31 : tag[b * 256 + l - 1];
      gval += E[l * 33 + tg] + Ts[prev * 33 + tg];
    }
  }
#pragma unroll
  for (int o = 32; o > 0; o >>= 1) gval += __shfl_down(gval, o);
  int c = lane;
  float tcol[33];
  if (c < 33) {
#pragma unroll
    for (int p = 0; p < 33; ++p) tcol[p] = Ts[p * 33 + c];
    sc[c] = E[c] + tcol[31];   // START=31
  }
  __syncthreads();
#pragma unroll 1
  for (int t = 1; t < len; ++t) {
    float nv = 0.f;
    if (c < 33) {
      float ec = E[t * 33 + c];
      float vb[33];
      float m0 = -3.0e38f, m1 = -3.0e38f, m2 = -3.0e38f, m3 = -3.0e38f;
#pragma unroll
      for (int p = 0; p < 32; p += 4) {
        vb[p]     = sc[p]     + tcol[p];     m0 = fmaxf(m0, vb[p]);
        vb[p + 1] = sc[p + 1] + tcol[p + 1]; m1 = fmaxf(m1, vb[p + 1]);
        vb[p + 2] = sc[p + 2] + tcol[p + 2]; m2 = fmaxf(m2, vb[p + 2]);
        vb[p + 3] = sc[p + 3] + tcol[p + 3]; m3 = fmaxf(m3, vb[p + 3]);
      }
      vb[32] = sc[32] + tcol[32];
      float mx = fmaxf(fmaxf(fmaxf(m0, m1), fmaxf(m2, m3)), vb[32]);
      float s0 = 0.f, s1 = 0.f, s2 = 0.f, s3 = 0.f;
#pragma unroll
      for (int p = 0; p < 32; p += 4) {
        s0 += __expf(vb[p] - mx);     s1 += __expf(vb[p + 1] - mx);
        s2 += __expf(vb[p + 2] - mx); s3 += __expf(vb[p + 3] - mx);
      }
      s0 += __expf(vb[32] - mx);
      nv = ec + mx + __logf((s0 + s1) + (s2 + s3));
    }
    __syncthreads();
    if (c < 33) sc[c] = nv;
    __syncthreads();
  }
  if (lane == 0) part[b] = sc[32] - gval;   // END=32
}

// ---------------- finalize: loss = sum(part) / 128 ----------------
__global__ __launch_bounds__(64) void fin_k(const float* __restrict__ part,
    float* __restrict__ out) {
  int l = threadIdx.x;
  float v = part[l] + part[l + 64];
#pragma unroll
  for (int o = 32; o > 0; o >>= 1) v += __shfl_down(v, o);
  if (l == 0) out[0] = v / 128.f;
}

extern "C" void kernel_launch(void* const* d_in, const int* in_sizes, int n_in,
                              void* d_out, int out_size, void* d_ws, size_t ws_size,
                              hipStream_t stream) {
  const int*   batch_data   = (const int*)d_in[0];
  const int*   batch_onerad = (const int*)d_in[1];
  const int*   batch_tag    = (const int*)d_in[2];
  const float* embed        = (const float*)d_in[3];
  const float* rad_embed    = (const float*)d_in[4];
  const float* Wih_f = (const float*)d_in[5];
  const float* Whh_f = (const float*)d_in[6];
  const float* bih_f = (const float*)d_in[7];
  const float* bhh_f = (const float*)d_in[8];
  const float* Wih_b = (const float*)d_in[9];
  const float* Whh_b = (const float*)d_in[10];
  const float* bih_b = (const float*)d_in[11];
  const float* bhh_b = (const float*)d_in[12];
  const float* Wcls  = (const float*)d_in[13];
  const float* bcls  = (const float*)d_in[14];
  const float* trans = (const float*)d_in[15];

  // workspace layout (~203.9 MB)
  char* ws = (char*)d_ws;
  u16*   Apack = (u16*)  (ws + 0);            // 29360128
  u16*   X2    = (u16*)  (ws + 29360128);     // 134217728 (pair-contiguous xg)
  u16*   WihP  = (u16*)  (ws + 163577856);    // 1835008
  unsigned int* WhhF8 = (unsigned int*)(ws + 165412864); // 524288
  float* biasP = (float*)(ws + 165937152);    // 8192
  u16*   WclsP = (u16*)  (ws + 165945344);    // 49152
  u16*   outh  = (u16*)  (ws + 165994496);    // 33554432
  float* emiB  = (float*)(ws + 199548928);    // 4325376
  float* part  = (float*)(ws + 203874304);    // 512

  pack_all<<<18536, 256, 0, stream>>>(Wih_f, Wih_b, Whh_f, Whh_b, bih_f, bhh_f,
                                      bih_b, bhh_b, Wcls, batch_data, batch_onerad,
                                      embed, rad_embed, WihP, WhhF8, biasP, WclsP, Apack);
  gemm_xg<<<4096, 256, 0, stream>>>(Apack, WihP, biasP, X2);
  lstm_recur<<<32, 512, 0, stream>>>(X2, (const unsigned char*)WhhF8, outh);
  emis_k<<<512, 256, 0, stream>>>(outh, WclsP, bcls, emiB);
  crf2_k<<<128, 64, 0, stream>>>(batch_tag, emiB, trans, part);
  fin_k<<<1, 64, 0, stream>>>(part, (float*)d_out);
}

// Round 17
// 614.879 us; speedup vs baseline: 1.3471x; 1.1424x over previous
//
#include <hip/hip_runtime.h>
#include <hip/hip_bf16.h>
#include <stdint.h>

// LSTM-CRF forward loss. B=128 L=256 V=6000 E=128 RV=300 RD=100 H=256 C=33
// DIN=428 (pad to 448). Pipeline:
//   pack_all (weights+A) -> gemm_xg (pair-contiguous X2, full-line stores)
//   -> lstm_recur (128 wg x 512 thr; 2-row chunks; 1 output/lane; Whh pinned)
//   -> emis_k -> crf2_k (LDS emissions + golden fused) -> fin_k

typedef unsigned short u16;
typedef __attribute__((ext_vector_type(8))) __bf16 bf16x8;
typedef __attribute__((ext_vector_type(4))) float f32x4;

struct __align__(8) u16x4 { u16 x, y, z, w; };

typedef const void __attribute__((address_space(1))) gas_t;
typedef void __attribute__((address_space(3))) las_t;

static __device__ __forceinline__ void gload16(const void* g, void* l) {
  __builtin_amdgcn_global_load_lds((gas_t*)g, (las_t*)l, 16, 0, 0);
}

static __device__ __forceinline__ u16 f2b(float x) {
  uint32_t u = __builtin_bit_cast(uint32_t, x);
  uint32_t r = u + 0x7fffu + ((u >> 16) & 1u);
  return (u16)(r >> 16);
}
static __device__ __forceinline__ float b2lo(uint32_t u) {
  return __builtin_bit_cast(float, u << 16);
}
static __device__ __forceinline__ float b2hi(uint32_t u) {
  return __builtin_bit_cast(float, u & 0xffff0000u);
}
static __device__ __forceinline__ uint32_t pkbf16(float lo, float hi) {
  uint32_t w;
  asm("v_cvt_pk_bf16_f32 %0, %1, %2" : "=v"(w) : "v"(lo), "v"(hi));
  return w;
}
static __device__ __forceinline__ float sigf(float x) {
  return __builtin_amdgcn_rcpf(1.f + __expf(-x));
}
static __device__ __forceinline__ float tanh_(float x) {
  return 1.f - 2.f * __builtin_amdgcn_rcpf(1.f + __expf(2.f * x));
}
static __device__ __forceinline__ f32x4 MFMA(bf16x8 a, bf16x8 b, f32x4 c) {
  return __builtin_amdgcn_mfma_f32_16x16x32_bf16(a, b, c, 0, 0, 0);
}

// ---------------- pack_all: weights (blocks < 4200) + A gather (rest) ----------------
__global__ __launch_bounds__(256) void pack_all(
    const float* __restrict__ Wih_f, const float* __restrict__ Wih_b,
    const float* __restrict__ Whh_f, const float* __restrict__ Whh_b,
    const float* __restrict__ bih_f, const float* __restrict__ bhh_f,
    const float* __restrict__ bih_b, const float* __restrict__ bhh_b,
    const float* __restrict__ Wcls,
    const int* __restrict__ data, const int* __restrict__ onerad,
    const float* __restrict__ embed, const float* __restrict__ rad,
    u16* __restrict__ WihP, unsigned int* __restrict__ WhhF8,
    float* __restrict__ biasP, u16* __restrict__ WclsP, u16* __restrict__ A) {
  if (blockIdx.x < 4200) {
    int idx = blockIdx.x * 256 + threadIdx.x;
    if (idx < 917504) {                       // 2*1024*448
      int d = idx / 458752;
      int rem = idx - d * 458752;
      int r = rem / 448, k = rem - r * 448;
      const float* W = d ? Wih_b : Wih_f;
      WihP[idx] = (k < 428) ? f2b(W[r * 428 + k]) : (u16)0;
    } else if (idx < 919552) {                // bias 2048
      int j = idx - 917504;
      int r = j & 1023;
      biasP[j] = (j >> 10) ? (bih_b[r] + bhh_b[r]) : (bih_f[r] + bhh_f[r]);
    } else if (idx < 944128) {                // Wcls 48*512
      int j = idx - 919552;
      int r = j >> 9, k = j & 511;
      WclsP[j] = (r < 33) ? f2b(Wcls[r * 512 + k]) : (u16)0;
    } else if (idx < 1075200) {               // WhhF8: 131072 dwords
      int q = idx - 944128;
      int eh = q & 1, li = (q >> 1) & 63, fi = (q >> 7) & 63;
      int v = (q >> 13) & 7, dd = q >> 16;
      int l16 = li & 15, g = li >> 4;
      int kf = fi & 7, gj = fi >> 3;
      int gate = gj >> 1, jf = gj & 1;
      int row = gate * 256 + v * 32 + jf * 16 + l16;
      int col = kf * 32 + g * 8 + eh * 4;
      const float* W = dd ? Whh_b : Whh_f;
      float4 f = *(const float4*)(W + (size_t)row * 256 + col);
      unsigned int r01 = __builtin_amdgcn_cvt_pk_fp8_f32(f.x, f.y, 0u, false) & 0xffffu;
      unsigned int r23 = __builtin_amdgcn_cvt_pk_fp8_f32(f.z, f.w, 0u, false) & 0xffffu;
      WhhF8[q] = r01 | (r23 << 16);
    }
  } else {
    int idx = (blockIdx.x - 4200) * 256 + threadIdx.x;   // 32768*112 total
    int m = idx / 112;
    int c = idx - m * 112;
    int k0 = c * 4;
    float4 vv;
    if (k0 < 128)      vv = *(const float4*)(embed + (size_t)data[m] * 128 + k0);
    else if (k0 < 228) vv = *(const float4*)(rad + (size_t)onerad[m] * 100 + (k0 - 128));
    else if (k0 < 328) vv = *(const float4*)(rad + (size_t)onerad[32768 + m] * 100 + (k0 - 228));
    else if (k0 < 428) vv = *(const float4*)(rad + (size_t)onerad[65536 + m] * 100 + (k0 - 328));
    else               vv = make_float4(0.f, 0.f, 0.f, 0.f);
    u16x4 o4 = { f2b(vv.x), f2b(vv.y), f2b(vv.z), f2b(vv.w) };
    *(u16x4*)(A + (size_t)m * 448 + k0) = o4;
  }
}

// ---------------- xg GEMM: X2 = pair-contiguous(A @ Wih^T + bias) ----------------
// X2 u16 layout per d (33554432 u16): idx = R*1024 + gate*256 + v*32 + l16*2 + jf.
__global__ __launch_bounds__(256) void gemm_xg(const u16* __restrict__ A,
    const u16* __restrict__ Bw, const float* __restrict__ bias,
    u16* __restrict__ X2) {
  __shared__ u16 As[4096];
  __shared__ u16 Bs[4096];
  int bid = blockIdx.x;
  int mt = bid >> 4, nt = bid & 15;
  int m0 = mt * 128, n0 = nt * 128;
  int tid = threadIdx.x;
  int w = tid >> 6, lane = tid & 63, l16 = lane & 15, g = lane >> 4;
  int wr = w >> 1, wc = w & 1;
  int srow = tid >> 2, sch = tid & 3;
  f32x4 zero4 = {0.f, 0.f, 0.f, 0.f};
  f32x4 acc[4][4];
#pragma unroll
  for (int i = 0; i < 4; ++i)
#pragma unroll
    for (int j = 0; j < 4; ++j) acc[i][j] = zero4;
  for (int kk = 0; kk < 14; ++kk) {
    int kb = kk * 32;
    gload16(A + (size_t)(m0 + srow) * 448 + kb + sch * 8, (char*)As + tid * 16);
    gload16(A + (size_t)(m0 + srow + 64) * 448 + kb + sch * 8, (char*)As + 4096 + tid * 16);
    gload16(Bw + (size_t)(n0 + srow) * 448 + kb + sch * 8, (char*)Bs + tid * 16);
    gload16(Bw + (size_t)(n0 + srow + 64) * 448 + kb + sch * 8, (char*)Bs + 4096 + tid * 16);
    __syncthreads();
    bf16x8 af[4], bfr[4];
#pragma unroll
    for (int i = 0; i < 4; ++i) {
      af[i]  = *(const bf16x8*)((const char*)As + (wr * 64 + i * 16 + l16) * 64 + g * 16);
      bfr[i] = *(const bf16x8*)((const char*)Bs + (wc * 64 + i * 16 + l16) * 64 + g * 16);
    }
#pragma unroll
    for (int i = 0; i < 4; ++i)
#pragma unroll
      for (int j = 0; j < 4; ++j)
        acc[i][j] = MFMA(af[i], bfr[j], acc[i][j]);
    __syncthreads();
  }
  float bv[4];
#pragma unroll
  for (int j = 0; j < 4; ++j) bv[j] = bias[n0 + wc * 64 + j * 16 + l16];
  int dd = n0 >> 10;
#pragma unroll
  for (int i = 0; i < 4; ++i)
#pragma unroll
    for (int jp = 0; jp < 2; ++jp) {
      int j0 = jp * 2;
      int c = (n0 + wc * 64 + j0 * 16 + l16) & 1023;   // jf=0 member
      int gate = c >> 8, vv = (c >> 5) & 7, lc = c & 15;
      size_t base = (size_t)dd * 33554432 + (size_t)gate * 256 + vv * 32 + lc * 2;
#pragma unroll
      for (int r = 0; r < 4; ++r) {
        int row = m0 + wr * 64 + i * 16 + g * 4 + r;
        *(unsigned int*)(X2 + base + (size_t)row * 1024) =
            pkbf16(acc[i][j0][r] + bv[j0], acc[i][j0 + 1][r] + bv[j0 + 1]);
      }
    }
}

// ---------------- LSTM recurrence: 128 blocks, 2-row chunks, 1 output/lane ----------------
// 128 blocks (2 dir x 64 chunks of 2 batch rows) x 512 thr. Whh pinned
// (64 longs/lane). MFMA M=16 tile, rows 2-15 zero. Lane owns ONE output:
// row = lane>>5, col = v*32 + jf*16 + l16 (jf=(lane>>4)&1, l16=lane&15).
// Redistribution: uniform-index shfl from lanes 0-15 (rows 0/1 in regs 0/1).
#define PIN(n) long q##n; \
  asm volatile("global_load_dwordx2 %0, %1, off" : "=v"(q##n) : "v"(wbase + (n) * 512));
#define MMG(acc, gj, bn) \
  acc[gj] = __builtin_amdgcn_mfma_f32_16x16x32_fp8_fp8(a, bn, acc[gj], 0, 0, 0);
#define KSTEP(acc, fr, kf, B0, B1, B2, B3, B4, B5, B6, B7) { \
  long a = fr[(kf) * 64 + lane]; \
  MMG(acc, 0, B0) MMG(acc, 1, B1) MMG(acc, 2, B2) MMG(acc, 3, B3) \
  MMG(acc, 4, B4) MMG(acc, 5, B5) MMG(acc, 6, B6) MMG(acc, 7, B7) }
#define MFMA_PHASE(acc, hf) { \
  const long* fr = (const long*)(hf); \
  acc[0] = zero4; acc[1] = zero4; acc[2] = zero4; acc[3] = zero4; \
  acc[4] = zero4; acc[5] = zero4; acc[6] = zero4; acc[7] = zero4; \
  KSTEP(acc, fr, 0, q0, q8,  q16, q24, q32, q40, q48, q56) \
  KSTEP(acc, fr, 1, q1, q9,  q17, q25, q33, q41, q49, q57) \
  KSTEP(acc, fr, 2, q2, q10, q18, q26, q34, q42, q50, q58) \
  KSTEP(acc, fr, 3, q3, q11, q19, q27, q35, q43, q51, q59) \
  KSTEP(acc, fr, 4, q4, q12, q20, q28, q36, q44, q52, q60) \
  KSTEP(acc, fr, 5, q5, q13, q21, q29, q37, q45, q53, q61) \
  KSTEP(acc, fr, 6, q6, q14, q22, q30, q38, q46, q54, q62) \
  KSTEP(acc, fr, 7, q7, q15, q23, q31, q39, q47, q55, q63) }
// GVAL(gate): gate pre-activation for this lane's (row, col), + xg from px
#define GVAL(gate, dst) { \
  float a00 = __shfl(accA[(gate) * 2][0],     srcl); \
  float a01 = __shfl(accA[(gate) * 2][1],     srcl); \
  float a10 = __shfl(accA[(gate) * 2 + 1][0], srcl); \
  float a11 = __shfl(accA[(gate) * 2 + 1][1], srcl); \
  float s0 = hirow ? a01 : a00; \
  float s1 = hirow ? a11 : a10; \
  float xv = hijf ? b2hi(pxA[gate]) : b2lo(pxA[gate]); \
  dst = (hijf ? s1 : s0) + xv; }
#define FENCE { __builtin_amdgcn_sched_barrier(0); \
  asm volatile("s_waitcnt lgkmcnt(0)"); \
  __builtin_amdgcn_s_barrier(); \
  __builtin_amdgcn_sched_barrier(0); }

__global__ __launch_bounds__(512, 1) void lstm_recur(const u16* __restrict__ xg,
    const unsigned char* __restrict__ WhhF8, u16* __restrict__ outh) {
  __shared__ unsigned char hfA[2][4096];
  int blk = blockIdx.x;
  int d = blk >> 6, ch = blk & 63;
  int rowA0 = ch * 2;
  int tid = threadIdx.x;
  int v = tid >> 6, lane = tid & 63, l16 = lane & 15, g = lane >> 4;
  int row = lane >> 5;           // 0/1
  int jf = (lane >> 4) & 1;
  bool hirow = (row == 1), hijf = (jf == 1);
  int srcl = l16;
  int col = v * 32 + jf * 16 + l16;

  const char* wbase = (const char*)WhhF8 + ((size_t)(d * 8 + v) * 4096 + lane) * 8;
  PIN(0)  PIN(1)  PIN(2)  PIN(3)  PIN(4)  PIN(5)  PIN(6)  PIN(7)
  PIN(8)  PIN(9)  PIN(10) PIN(11) PIN(12) PIN(13) PIN(14) PIN(15)
  PIN(16) PIN(17) PIN(18) PIN(19) PIN(20) PIN(21) PIN(22) PIN(23)
  PIN(24) PIN(25) PIN(26) PIN(27) PIN(28) PIN(29) PIN(30) PIN(31)
  PIN(32) PIN(33) PIN(34) PIN(35) PIN(36) PIN(37) PIN(38) PIN(39)
  PIN(40) PIN(41) PIN(42) PIN(43) PIN(44) PIN(45) PIN(46) PIN(47)
  PIN(48) PIN(49) PIN(50) PIN(51) PIN(52) PIN(53) PIN(54) PIN(55)
  PIN(56) PIN(57) PIN(58) PIN(59) PIN(60) PIN(61) PIN(62) PIN(63)

  for (int i = tid; i < 2048; i += 512) ((int*)hfA)[i] = 0;

  int t0 = d ? 255 : 0;
  int tpx = d ? -2048 : 2048;    // bytes per t-step in X2 (1024 u16/row-step)
  int tob = d ? -1024 : 1024;    // bytes per t-step in outh (512 u16)

  const char* pb = (const char*)xg + (size_t)d * 67108864
      + ((size_t)(rowA0 + row) * 256 + t0) * 2048 + v * 64 + l16 * 4;
  char* sb = (char*)outh
      + (((size_t)(rowA0 + row) * 256 + t0) * 512 + d * 256 + col) * 2;
  int fwoff = (v * 64 + jf * 32 + (l16 >> 3) * 16 + row) * 8 + (l16 & 7);

  unsigned int pxA[4];
  pxA[0] = *(const unsigned int*)(pb);
  pxA[1] = *(const unsigned int*)(pb + 512);
  pxA[2] = *(const unsigned int*)(pb + 1024);
  pxA[3] = *(const unsigned int*)(pb + 1536);

  asm volatile("s_waitcnt vmcnt(0)" ::: "memory");
  __builtin_amdgcn_sched_barrier(0);

  f32x4 zero4 = {0.f, 0.f, 0.f, 0.f};
  float cst = 0.f;
  f32x4 accA[8];
  __syncthreads();

#pragma unroll 1
  for (int tt = 0; tt < 256; ++tt) {
    int p = tt & 1;
    MFMA_PHASE(accA, &hfA[p][0]);
    // TRANS: one output per lane
    {
      float iv, fv, gv, ov;
      GVAL(0, iv) GVAL(1, fv) GVAL(2, gv) GVAL(3, ov)
      float cn = sigf(fv) * cst + sigf(iv) * tanh_(gv);
      cst = cn;
      float hv = sigf(ov) * tanh_(cn);
      hfA[p ^ 1][fwoff] =
          (unsigned char)__builtin_amdgcn_cvt_pk_fp8_f32(hv, hv, 0u, false);
      *(u16*)sb = f2b(hv);
    }
    sb += tob; pb += tpx;
    pxA[0] = *(const unsigned int*)(pb);
    pxA[1] = *(const unsigned int*)(pb + 512);
    pxA[2] = *(const unsigned int*)(pb + 1024);
    pxA[3] = *(const unsigned int*)(pb + 1536);
    FENCE;
  }
}

// ---------------- emission: [32768][33] f32 = outh @ Wcls^T + bcls ----------------
__global__ __launch_bounds__(256) void emis_k(const u16* __restrict__ outh,
    const u16* __restrict__ WclsP, const float* __restrict__ bcls,
    float* __restrict__ emiB) {
  int tid = threadIdx.x;
  int w = tid >> 6, lane = tid & 63, l16 = lane & 15, g = lane >> 4;
  int mrow = blockIdx.x * 64 + w * 16;
  f32x4 zero4 = {0.f, 0.f, 0.f, 0.f};
  f32x4 acc[3] = {zero4, zero4, zero4};
#pragma unroll
  for (int kf = 0; kf < 16; ++kf) {
    bf16x8 a = *(const bf16x8*)(outh + (size_t)(mrow + l16) * 512 + kf * 32 + g * 8);
#pragma unroll
    for (int nf = 0; nf < 3; ++nf) {
      bf16x8 bb = *(const bf16x8*)(WclsP + (size_t)(nf * 16 + l16) * 512 + kf * 32 + g * 8);
      acc[nf] = MFMA(a, bb, acc[nf]);
    }
  }
#pragma unroll
  for (int nf = 0; nf < 3; ++nf) {
    int c = nf * 16 + l16;
    if (c < 33) {
      float bc = bcls[c];
#pragma unroll
      for (int r = 0; r < 4; ++r)
        emiB[(size_t)(mrow + g * 4 + r) * 33 + c] = acc[nf][r] + bc;
    }
  }
}

// ---------------- CRF forward + golden, fused; emissions LDS-resident ----------------
__global__ __launch_bounds__(64) void crf2_k(const int* __restrict__ tag,
    const float* __restrict__ emiB, const float* __restrict__ T,
    float* __restrict__ part) {
  int b = blockIdx.x;
  int lane = threadIdx.x;
  __shared__ float Ts[1089];
  __shared__ float E[8448];
  __shared__ float sc[33];
  for (int i = lane; i < 1089; i += 64) Ts[i] = T[i];
  {
    const float* eb = emiB + (size_t)b * 8448;
    for (int i = lane; i < 8448; i += 64) E[i] = eb[i];
  }
  int cnt = 0;
  for (int i = lane; i < 256; i += 64) cnt += (tag[b * 256 + i] != 0) ? 1 : 0;
#pragma unroll
  for (int o = 1; o < 64; o <<= 1) cnt += __shfl_xor(cnt, o);
  int len = cnt;
  __syncthreads();
  float gval = 0.f;
  for (int l = lane; l < 256; l += 64) {
    int tg = tag[b * 256 + l];
    if (tg != 0) {
      int prev = (l == 0) ? 31 : tag[b * 256 + l - 1];
      gval += E[l * 33 + tg] + Ts[prev * 33 + tg];
    }
  }
#pragma unroll
  for (int o = 32; o > 0; o >>= 1) gval += __shfl_down(gval, o);
  int c = lane;
  float tcol[33];
  if (c < 33) {
#pragma unroll
    for (int p = 0; p < 33; ++p) tcol[p] = Ts[p * 33 + c];
    sc[c] = E[c] + tcol[31];   // START=31
  }
  __syncthreads();
#pragma unroll 1
  for (int t = 1; t < len; ++t) {
    float nv = 0.f;
    if (c < 33) {
      float ec = E[t * 33 + c];
      float vb[33];
      float m0 = -3.0e38f, m1 = -3.0e38f, m2 = -3.0e38f, m3 = -3.0e38f;
#pragma unroll
      for (int p = 0; p < 32; p += 4) {
        vb[p]     = sc[p]     + tcol[p];     m0 = fmaxf(m0, vb[p]);
        vb[p + 1] = sc[p + 1] + tcol[p + 1]; m1 = fmaxf(m1, vb[p + 1]);
        vb[p + 2] = sc[p + 2] + tcol[p + 2]; m2 = fmaxf(m2, vb[p + 2]);
        vb[p + 3] = sc[p + 3] + tcol[p + 3]; m3 = fmaxf(m3, vb[p + 3]);
      }
      vb[32] = sc[32] + tcol[32];
      float mx = fmaxf(fmaxf(fmaxf(m0, m1), fmaxf(m2, m3)), vb[32]);
      float s0 = 0.f, s1 = 0.f, s2 = 0.f, s3 = 0.f;
#pragma unroll
      for (int p = 0; p < 32; p += 4) {
        s0 += __expf(vb[p] - mx);     s1 += __expf(vb[p + 1] - mx);
        s2 += __expf(vb[p + 2] - mx); s3 += __expf(vb[p + 3] - mx);
      }
      s0 += __expf(vb[32] - mx);
      nv = ec + mx + __logf((s0 + s1) + (s2 + s3));
    }
    __syncthreads();
    if (c < 33) sc[c] = nv;
    __syncthreads();
  }
  if (lane == 0) part[b] = sc[32] - gval;   // END=32
}

// ---------------- finalize: loss = sum(part) / 128 ----------------
__global__ __launch_bounds__(64) void fin_k(const float* __restrict__ part,
    float* __restrict__ out) {
  int l = threadIdx.x;
  float v = part[l] + part[l + 64];
#pragma unroll
  for (int o = 32; o > 0; o >>= 1) v += __shfl_down(v, o);
  if (l == 0) out[0] = v / 128.f;
}

extern "C" void kernel_launch(void* const* d_in, const int* in_sizes, int n_in,
                              void* d_out, int out_size, void* d_ws, size_t ws_size,
                              hipStream_t stream) {
  const int*   batch_data   = (const int*)d_in[0];
  const int*   batch_onerad = (const int*)d_in[1];
  const int*   batch_tag    = (const int*)d_in[2];
  const float* embed        = (const float*)d_in[3];
  const float* rad_embed    = (const float*)d_in[4];
  const float* Wih_f = (const float*)d_in[5];
  const float* Whh_f = (const float*)d_in[6];
  const float* bih_f = (const float*)d_in[7];
  const float* bhh_f = (const float*)d_in[8];
  const float* Wih_b = (const float*)d_in[9];
  const float* Whh_b = (const float*)d_in[10];
  const float* bih_b = (const float*)d_in[11];
  const float* bhh_b = (const float*)d_in[12];
  const float* Wcls  = (const float*)d_in[13];
  const float* bcls  = (const float*)d_in[14];
  const float* trans = (const float*)d_in[15];

  // workspace layout (~203.9 MB)
  char* ws = (char*)d_ws;
  u16*   Apack = (u16*)  (ws + 0);            // 29360128
  u16*   X2    = (u16*)  (ws + 29360128);     // 134217728 (pair-contiguous xg)
  u16*   WihP  = (u16*)  (ws + 163577856);    // 1835008
  unsigned int* WhhF8 = (unsigned int*)(ws + 165412864); // 524288
  float* biasP = (float*)(ws + 165937152);    // 8192
  u16*   WclsP = (u16*)  (ws + 165945344);    // 49152
  u16*   outh  = (u16*)  (ws + 165994496);    // 33554432
  float* emiB  = (float*)(ws + 199548928);    // 4325376
  float* part  = (float*)(ws + 203874304);    // 512

  pack_all<<<18536, 256, 0, stream>>>(Wih_f, Wih_b, Whh_f, Whh_b, bih_f, bhh_f,
                                      bih_b, bhh_b, Wcls, batch_data, batch_onerad,
                                      embed, rad_embed, WihP, WhhF8, biasP, WclsP, Apack);
  gemm_xg<<<4096, 256, 0, stream>>>(Apack, WihP, biasP, X2);
  lstm_recur<<<128, 512, 0, stream>>>(X2, (const unsigned char*)WhhF8, outh);
  emis_k<<<512, 256, 0, stream>>>(outh, WclsP, bcls, emiB);
  crf2_k<<<128, 64, 0, stream>>>(batch_tag, emiB, trans, part);
  fin_k<<<1, 64, 0, stream>>>(part, (float*)d_out);
}

// Round 18
// 584.572 us; speedup vs baseline: 1.4169x; 1.0518x over previous
//
#include <hip/hip_runtime.h>
#include <hip/hip_bf16.h>
#include <stdint.h>

// LSTM-CRF forward loss. B=128 L=256 V=6000 E=128 RV=300 RD=100 H=256 C=33
// DIN=428 (pad to 448). Pipeline:
//   pack_all (weights+A) -> gemm_xg (pair-contiguous X2, full-line stores)
//   -> lstm_recur (128 wg x 512 thr; 2-row chunks; 1 output/lane; Whh pinned;
//      afr[8] batched LDS preload) -> emis_k -> crf2_k -> fin_k

typedef unsigned short u16;
typedef __attribute__((ext_vector_type(8))) __bf16 bf16x8;
typedef __attribute__((ext_vector_type(4))) float f32x4;

struct __align__(8) u16x4 { u16 x, y, z, w; };

typedef const void __attribute__((address_space(1))) gas_t;
typedef void __attribute__((address_space(3))) las_t;

static __device__ __forceinline__ void gload16(const void* g, void* l) {
  __builtin_amdgcn_global_load_lds((gas_t*)g, (las_t*)l, 16, 0, 0);
}

static __device__ __forceinline__ u16 f2b(float x) {
  uint32_t u = __builtin_bit_cast(uint32_t, x);
  uint32_t r = u + 0x7fffu + ((u >> 16) & 1u);
  return (u16)(r >> 16);
}
static __device__ __forceinline__ float b2lo(uint32_t u) {
  return __builtin_bit_cast(float, u << 16);
}
static __device__ __forceinline__ float b2hi(uint32_t u) {
  return __builtin_bit_cast(float, u & 0xffff0000u);
}
static __device__ __forceinline__ uint32_t pkbf16(float lo, float hi) {
  uint32_t w;
  asm("v_cvt_pk_bf16_f32 %0, %1, %2" : "=v"(w) : "v"(lo), "v"(hi));
  return w;
}
static __device__ __forceinline__ float sigf(float x) {
  return __builtin_amdgcn_rcpf(1.f + __expf(-x));
}
static __device__ __forceinline__ float tanh_(float x) {
  return 1.f - 2.f * __builtin_amdgcn_rcpf(1.f + __expf(2.f * x));
}
static __device__ __forceinline__ f32x4 MFMA(bf16x8 a, bf16x8 b, f32x4 c) {
  return __builtin_amdgcn_mfma_f32_16x16x32_bf16(a, b, c, 0, 0, 0);
}

// ---------------- pack_all: weights (blocks < 4200) + A gather (rest) ----------------
__global__ __launch_bounds__(256) void pack_all(
    const float* __restrict__ Wih_f, const float* __restrict__ Wih_b,
    const float* __restrict__ Whh_f, const float* __restrict__ Whh_b,
    const float* __restrict__ bih_f, const float* __restrict__ bhh_f,
    const float* __restrict__ bih_b, const float* __restrict__ bhh_b,
    const float* __restrict__ Wcls,
    const int* __restrict__ data, const int* __restrict__ onerad,
    const float* __restrict__ embed, const float* __restrict__ rad,
    u16* __restrict__ WihP, unsigned int* __restrict__ WhhF8,
    float* __restrict__ biasP, u16* __restrict__ WclsP, u16* __restrict__ A) {
  if (blockIdx.x < 4200) {
    int idx = blockIdx.x * 256 + threadIdx.x;
    if (idx < 917504) {                       // 2*1024*448
      int d = idx / 458752;
      int rem = idx - d * 458752;
      int r = rem / 448, k = rem - r * 448;
      const float* W = d ? Wih_b : Wih_f;
      WihP[idx] = (k < 428) ? f2b(W[r * 428 + k]) : (u16)0;
    } else if (idx < 919552) {                // bias 2048
      int j = idx - 917504;
      int r = j & 1023;
      biasP[j] = (j >> 10) ? (bih_b[r] + bhh_b[r]) : (bih_f[r] + bhh_f[r]);
    } else if (idx < 944128) {                // Wcls 48*512
      int j = idx - 919552;
      int r = j >> 9, k = j & 511;
      WclsP[j] = (r < 33) ? f2b(Wcls[r * 512 + k]) : (u16)0;
    } else if (idx < 1075200) {               // WhhF8: 131072 dwords
      int q = idx - 944128;
      int eh = q & 1, li = (q >> 1) & 63, fi = (q >> 7) & 63;
      int v = (q >> 13) & 7, dd = q >> 16;
      int l16 = li & 15, g = li >> 4;
      int kf = fi & 7, gj = fi >> 3;
      int gate = gj >> 1, jf = gj & 1;
      int row = gate * 256 + v * 32 + jf * 16 + l16;
      int col = kf * 32 + g * 8 + eh * 4;
      const float* W = dd ? Whh_b : Whh_f;
      float4 f = *(const float4*)(W + (size_t)row * 256 + col);
      unsigned int r01 = __builtin_amdgcn_cvt_pk_fp8_f32(f.x, f.y, 0u, false) & 0xffffu;
      unsigned int r23 = __builtin_amdgcn_cvt_pk_fp8_f32(f.z, f.w, 0u, false) & 0xffffu;
      WhhF8[q] = r01 | (r23 << 16);
    }
  } else {
    int idx = (blockIdx.x - 4200) * 256 + threadIdx.x;   // 32768*112 total
    int m = idx / 112;
    int c = idx - m * 112;
    int k0 = c * 4;
    float4 vv;
    if (k0 < 128)      vv = *(const float4*)(embed + (size_t)data[m] * 128 + k0);
    else if (k0 < 228) vv = *(const float4*)(rad + (size_t)onerad[m] * 100 + (k0 - 128));
    else if (k0 < 328) vv = *(const float4*)(rad + (size_t)onerad[32768 + m] * 100 + (k0 - 228));
    else if (k0 < 428) vv = *(const float4*)(rad + (size_t)onerad[65536 + m] * 100 + (k0 - 328));
    else               vv = make_float4(0.f, 0.f, 0.f, 0.f);
    u16x4 o4 = { f2b(vv.x), f2b(vv.y), f2b(vv.z), f2b(vv.w) };
    *(u16x4*)(A + (size_t)m * 448 + k0) = o4;
  }
}

// ---------------- xg GEMM: X2 = pair-contiguous(A @ Wih^T + bias) ----------------
// X2 u16 layout per d (33554432 u16): idx = R*1024 + gate*256 + v*32 + l16*2 + jf.
__global__ __launch_bounds__(256) void gemm_xg(const u16* __restrict__ A,
    const u16* __restrict__ Bw, const float* __restrict__ bias,
    u16* __restrict__ X2) {
  __shared__ u16 As[4096];
  __shared__ u16 Bs[4096];
  int bid = blockIdx.x;
  int mt = bid >> 4, nt = bid & 15;
  int m0 = mt * 128, n0 = nt * 128;
  int tid = threadIdx.x;
  int w = tid >> 6, lane = tid & 63, l16 = lane & 15, g = lane >> 4;
  int wr = w >> 1, wc = w & 1;
  int srow = tid >> 2, sch = tid & 3;
  f32x4 zero4 = {0.f, 0.f, 0.f, 0.f};
  f32x4 acc[4][4];
#pragma unroll
  for (int i = 0; i < 4; ++i)
#pragma unroll
    for (int j = 0; j < 4; ++j) acc[i][j] = zero4;
  for (int kk = 0; kk < 14; ++kk) {
    int kb = kk * 32;
    gload16(A + (size_t)(m0 + srow) * 448 + kb + sch * 8, (char*)As + tid * 16);
    gload16(A + (size_t)(m0 + srow + 64) * 448 + kb + sch * 8, (char*)As + 4096 + tid * 16);
    gload16(Bw + (size_t)(n0 + srow) * 448 + kb + sch * 8, (char*)Bs + tid * 16);
    gload16(Bw + (size_t)(n0 + srow + 64) * 448 + kb + sch * 8, (char*)Bs + 4096 + tid * 16);
    __syncthreads();
    bf16x8 af[4], bfr[4];
#pragma unroll
    for (int i = 0; i < 4; ++i) {
      af[i]  = *(const bf16x8*)((const char*)As + (wr * 64 + i * 16 + l16) * 64 + g * 16);
      bfr[i] = *(const bf16x8*)((const char*)Bs + (wc * 64 + i * 16 + l16) * 64 + g * 16);
    }
#pragma unroll
    for (int i = 0; i < 4; ++i)
#pragma unroll
      for (int j = 0; j < 4; ++j)
        acc[i][j] = MFMA(af[i], bfr[j], acc[i][j]);
    __syncthreads();
  }
  float bv[4];
#pragma unroll
  for (int j = 0; j < 4; ++j) bv[j] = bias[n0 + wc * 64 + j * 16 + l16];
  int dd = n0 >> 10;
#pragma unroll
  for (int i = 0; i < 4; ++i)
#pragma unroll
    for (int jp = 0; jp < 2; ++jp) {
      int j0 = jp * 2;
      int c = (n0 + wc * 64 + j0 * 16 + l16) & 1023;   // jf=0 member
      int gate = c >> 8, vv = (c >> 5) & 7, lc = c & 15;
      size_t base = (size_t)dd * 33554432 + (size_t)gate * 256 + vv * 32 + lc * 2;
#pragma unroll
      for (int r = 0; r < 4; ++r) {
        int row = m0 + wr * 64 + i * 16 + g * 4 + r;
        *(unsigned int*)(X2 + base + (size_t)row * 1024) =
            pkbf16(acc[i][j0][r] + bv[j0], acc[i][j0 + 1][r] + bv[j0 + 1]);
      }
    }
}

// ---------------- LSTM recurrence: 128 blocks, 2-row chunks, 1 output/lane ----------------
// 128 blocks (2 dir x 64 chunks of 2 batch rows) x 512 thr. Whh pinned
// (64 longs/lane). MFMA M=16 tile, rows 2-15 zero. Lane owns ONE output.
// MFMA phase: afr[8] preloaded (8 batched ds_read_b64, one lgkmcnt) then
// 64 dense MFMAs -- removes the 8x serial ds_read latency of r17.
#define PIN(n) long q##n; \
  asm volatile("global_load_dwordx2 %0, %1, off" : "=v"(q##n) : "v"(wbase + (n) * 512));
#define MMG(acc, gj, bn, a) \
  acc[gj] = __builtin_amdgcn_mfma_f32_16x16x32_fp8_fp8(a, bn, acc[gj], 0, 0, 0);
#define KSTEP(acc, a, B0, B1, B2, B3, B4, B5, B6, B7) { \
  MMG(acc, 0, B0, a) MMG(acc, 1, B1, a) MMG(acc, 2, B2, a) MMG(acc, 3, B3, a) \
  MMG(acc, 4, B4, a) MMG(acc, 5, B5, a) MMG(acc, 6, B6, a) MMG(acc, 7, B7, a) }
#define MFMA_PHASE(acc, hf) { \
  const long* fr = (const long*)(hf); \
  long afr0 = fr[lane];       long afr1 = fr[64 + lane]; \
  long afr2 = fr[128 + lane]; long afr3 = fr[192 + lane]; \
  long afr4 = fr[256 + lane]; long afr5 = fr[320 + lane]; \
  long afr6 = fr[384 + lane]; long afr7 = fr[448 + lane]; \
  asm volatile("s_waitcnt lgkmcnt(0)"); \
  __builtin_amdgcn_sched_barrier(0); \
  acc[0] = zero4; acc[1] = zero4; acc[2] = zero4; acc[3] = zero4; \
  acc[4] = zero4; acc[5] = zero4; acc[6] = zero4; acc[7] = zero4; \
  KSTEP(acc, afr0, q0, q8,  q16, q24, q32, q40, q48, q56) \
  KSTEP(acc, afr1, q1, q9,  q17, q25, q33, q41, q49, q57) \
  KSTEP(acc, afr2, q2, q10, q18, q26, q34, q42, q50, q58) \
  KSTEP(acc, afr3, q3, q11, q19, q27, q35, q43, q51, q59) \
  KSTEP(acc, afr4, q4, q12, q20, q28, q36, q44, q52, q60) \
  KSTEP(acc, afr5, q5, q13, q21, q29, q37, q45, q53, q61) \
  KSTEP(acc, afr6, q6, q14, q22, q30, q38, q46, q54, q62) \
  KSTEP(acc, afr7, q7, q15, q23, q31, q39, q47, q55, q63) }
// GVAL(gate): gate pre-activation for this lane's (row, col), + xg from px
#define GVAL(gate, dst) { \
  float a00 = __shfl(accA[(gate) * 2][0],     srcl); \
  float a01 = __shfl(accA[(gate) * 2][1],     srcl); \
  float a10 = __shfl(accA[(gate) * 2 + 1][0], srcl); \
  float a11 = __shfl(accA[(gate) * 2 + 1][1], srcl); \
  float s0 = hirow ? a01 : a00; \
  float s1 = hirow ? a11 : a10; \
  float xv = hijf ? b2hi(pxA[gate]) : b2lo(pxA[gate]); \
  dst = (hijf ? s1 : s0) + xv; }
#define FENCE { __builtin_amdgcn_sched_barrier(0); \
  asm volatile("s_waitcnt lgkmcnt(0)"); \
  __builtin_amdgcn_s_barrier(); \
  __builtin_amdgcn_sched_barrier(0); }

__global__ __launch_bounds__(512, 1) void lstm_recur(const u16* __restrict__ xg,
    const unsigned char* __restrict__ WhhF8, u16* __restrict__ outh) {
  __shared__ unsigned char hfA[2][4096];
  int blk = blockIdx.x;
  int d = blk >> 6, ch = blk & 63;
  int rowA0 = ch * 2;
  int tid = threadIdx.x;
  int v = tid >> 6, lane = tid & 63, l16 = lane & 15;
  int row = lane >> 5;           // 0/1
  int jf = (lane >> 4) & 1;
  bool hirow = (row == 1), hijf = (jf == 1);
  int srcl = l16;
  int col = v * 32 + jf * 16 + l16;

  const char* wbase = (const char*)WhhF8 + ((size_t)(d * 8 + v) * 4096 + lane) * 8;
  PIN(0)  PIN(1)  PIN(2)  PIN(3)  PIN(4)  PIN(5)  PIN(6)  PIN(7)
  PIN(8)  PIN(9)  PIN(10) PIN(11) PIN(12) PIN(13) PIN(14) PIN(15)
  PIN(16) PIN(17) PIN(18) PIN(19) PIN(20) PIN(21) PIN(22) PIN(23)
  PIN(24) PIN(25) PIN(26) PIN(27) PIN(28) PIN(29) PIN(30) PIN(31)
  PIN(32) PIN(33) PIN(34) PIN(35) PIN(36) PIN(37) PIN(38) PIN(39)
  PIN(40) PIN(41) PIN(42) PIN(43) PIN(44) PIN(45) PIN(46) PIN(47)
  PIN(48) PIN(49) PIN(50) PIN(51) PIN(52) PIN(53) PIN(54) PIN(55)
  PIN(56) PIN(57) PIN(58) PIN(59) PIN(60) PIN(61) PIN(62) PIN(63)

  for (int i = tid; i < 2048; i += 512) ((int*)hfA)[i] = 0;

  int t0 = d ? 255 : 0;
  int tpx = d ? -2048 : 2048;    // bytes per t-step in X2 (1024 u16/row-step)
  int tob = d ? -1024 : 1024;    // bytes per t-step in outh (512 u16)

  const char* pb = (const char*)xg + (size_t)d * 67108864
      + ((size_t)(rowA0 + row) * 256 + t0) * 2048 + v * 64 + l16 * 4;
  char* sb = (char*)outh
      + (((size_t)(rowA0 + row) * 256 + t0) * 512 + d * 256 + col) * 2;
  int fwoff = (v * 64 + jf * 32 + (l16 >> 3) * 16 + row) * 8 + (l16 & 7);

  unsigned int pxA[4];
  pxA[0] = *(const unsigned int*)(pb);
  pxA[1] = *(const unsigned int*)(pb + 512);
  pxA[2] = *(const unsigned int*)(pb + 1024);
  pxA[3] = *(const unsigned int*)(pb + 1536);

  asm volatile("s_waitcnt vmcnt(0)" ::: "memory");
  __builtin_amdgcn_sched_barrier(0);

  f32x4 zero4 = {0.f, 0.f, 0.f, 0.f};
  float cst = 0.f;
  f32x4 accA[8];
  __syncthreads();

#pragma unroll 1
  for (int tt = 0; tt < 256; ++tt) {
    int p = tt & 1;
    MFMA_PHASE(accA, &hfA[p][0]);
    // TRANS: one output per lane
    {
      float iv, fv, gv, ov;
      GVAL(0, iv) GVAL(1, fv) GVAL(2, gv) GVAL(3, ov)
      float cn = sigf(fv) * cst + sigf(iv) * tanh_(gv);
      cst = cn;
      float hv = sigf(ov) * tanh_(cn);
      hfA[p ^ 1][fwoff] =
          (unsigned char)__builtin_amdgcn_cvt_pk_fp8_f32(hv, hv, 0u, false);
      *(u16*)sb = f2b(hv);
    }
    sb += tob; pb += tpx;
    pxA[0] = *(const unsigned int*)(pb);
    pxA[1] = *(const unsigned int*)(pb + 512);
    pxA[2] = *(const unsigned int*)(pb + 1024);
    pxA[3] = *(const unsigned int*)(pb + 1536);
    FENCE;
  }
}

// ---------------- emission: [32768][33] f32 = outh @ Wcls^T + bcls ----------------
__global__ __launch_bounds__(256) void emis_k(const u16* __restrict__ outh,
    const u16* __restrict__ WclsP, const float* __restrict__ bcls,
    float* __restrict__ emiB) {
  int tid = threadIdx.x;
  int w = tid >> 6, lane = tid & 63, l16 = lane & 15, g = lane >> 4;
  int mrow = blockIdx.x * 64 + w * 16;
  f32x4 zero4 = {0.f, 0.f, 0.f, 0.f};
  f32x4 acc[3] = {zero4, zero4, zero4};
#pragma unroll
  for (int kf = 0; kf < 16; ++kf) {
    bf16x8 a = *(const bf16x8*)(outh + (size_t)(mrow + l16) * 512 + kf * 32 + g * 8);
#pragma unroll
    for (int nf = 0; nf < 3; ++nf) {
      bf16x8 bb = *(const bf16x8*)(WclsP + (size_t)(nf * 16 + l16) * 512 + kf * 32 + g * 8);
      acc[nf] = MFMA(a, bb, acc[nf]);
    }
  }
#pragma unroll
  for (int nf = 0; nf < 3; ++nf) {
    int c = nf * 16 + l16;
    if (c < 33) {
      float bc = bcls[c];
#pragma unroll
      for (int r = 0; r < 4; ++r)
        emiB[(size_t)(mrow + g * 4 + r) * 33 + c] = acc[nf][r] + bc;
    }
  }
}

// ---------------- CRF forward + golden, fused; emissions LDS-resident ----------------
__global__ __launch_bounds__(64) void crf2_k(const int* __restrict__ tag,
    const float* __restrict__ emiB, const float* __restrict__ T,
    float* __restrict__ part) {
  int b = blockIdx.x;
  int lane = threadIdx.x;
  __shared__ float Ts[1089];
  __shared__ float E[8448];
  __shared__ float sc[33];
  for (int i = lane; i < 1089; i += 64) Ts[i] = T[i];
  {
    const float* eb = emiB + (size_t)b * 8448;
    for (int i = lane; i < 8448; i += 64) E[i] = eb[i];
  }
  int cnt = 0;
  for (int i = lane; i < 256; i += 64) cnt += (tag[b * 256 + i] != 0) ? 1 : 0;
#pragma unroll
  for (int o = 1; o < 64; o <<= 1) cnt += __shfl_xor(cnt, o);
  int len = cnt;
  __syncthreads();
  float gval = 0.f;
  for (int l = lane; l < 256; l += 64) {
    int tg = tag[b * 256 + l];
    if (tg != 0) {
      int prev = (l == 0) ? 31 : tag[b * 256 + l - 1];
      gval += E[l * 33 + tg] + Ts[prev * 33 + tg];
    }
  }
#pragma unroll
  for (int o = 32; o > 0; o >>= 1) gval += __shfl_down(gval, o);
  int c = lane;
  float tcol[33];
  if (c < 33) {
#pragma unroll
    for (int p = 0; p < 33; ++p) tcol[p] = Ts[p * 33 + c];
    sc[c] = E[c] + tcol[31];   // START=31
  }
  __syncthreads();
#pragma unroll 1
  for (int t = 1; t < len; ++t) {
    float nv = 0.f;
    if (c < 33) {
      float ec = E[t * 33 + c];
      float vb[33];
      float m0 = -3.0e38f, m1 = -3.0e38f, m2 = -3.0e38f, m3 = -3.0e38f;
#pragma unroll
      for (int p = 0; p < 32; p += 4) {
        vb[p]     = sc[p]     + tcol[p];     m0 = fmaxf(m0, vb[p]);
        vb[p + 1] = sc[p + 1] + tcol[p + 1]; m1 = fmaxf(m1, vb[p + 1]);
        vb[p + 2] = sc[p + 2] + tcol[p + 2]; m2 = fmaxf(m2, vb[p + 2]);
        vb[p + 3] = sc[p + 3] + tcol[p + 3]; m3 = fmaxf(m3, vb[p + 3]);
      }
      vb[32] = sc[32] + tcol[32];
      float mx = fmaxf(fmaxf(fmaxf(m0, m1), fmaxf(m2, m3)), vb[32]);
      float s0 = 0.f, s1 = 0.f, s2 = 0.f, s3 = 0.f;
#pragma unroll
      for (int p = 0; p < 32; p += 4) {
        s0 += __expf(vb[p] - mx);     s1 += __expf(vb[p + 1] - mx);
        s2 += __expf(vb[p + 2] - mx); s3 += __expf(vb[p + 3] - mx);
      }
      s0 += __expf(vb[32] - mx);
      nv = ec + mx + __logf((s0 + s1) + (s2 + s3));
    }
    __syncthreads();
    if (c < 33) sc[c] = nv;
    __syncthreads();
  }
  if (lane == 0) part[b] = sc[32] - gval;   // END=32
}

// ---------------- finalize: loss = sum(part) / 128 ----------------
__global__ __launch_bounds__(64) void fin_k(const float* __restrict__ part,
    float* __restrict__ out) {
  int l = threadIdx.x;
  float v = part[l] + part[l + 64];
#pragma unroll
  for (int o = 32; o > 0; o >>= 1) v += __shfl_down(v, o);
  if (l == 0) out[0] = v / 128.f;
}

extern "C" void kernel_launch(void* const* d_in, const int* in_sizes, int n_in,
                              void* d_out, int out_size, void* d_ws, size_t ws_size,
                              hipStream_t stream) {
  const int*   batch_data   = (const int*)d_in[0];
  const int*   batch_onerad = (const int*)d_in[1];
  const int*   batch_tag    = (const int*)d_in[2];
  const float* embed        = (const float*)d_in[3];
  const float* rad_embed    = (const float*)d_in[4];
  const float* Wih_f = (const float*)d_in[5];
  const float* Whh_f = (const float*)d_in[6];
  const float* bih_f = (const float*)d_in[7];
  const float* bhh_f = (const float*)d_in[8];
  const float* Wih_b = (const float*)d_in[9];
  const float* Whh_b = (const float*)d_in[10];
  const float* bih_b = (const float*)d_in[11];
  const float* bhh_b = (const float*)d_in[12];
  const float* Wcls  = (const float*)d_in[13];
  const float* bcls  = (const float*)d_in[14];
  const float* trans = (const float*)d_in[15];

  // workspace layout (~203.9 MB)
  char* ws = (char*)d_ws;
  u16*   Apack = (u16*)  (ws + 0);            // 29360128
  u16*   X2    = (u16*)  (ws + 29360128);     // 134217728 (pair-contiguous xg)
  u16*   WihP  = (u16*)  (ws + 163577856);    // 1835008
  unsigned int* WhhF8 = (unsigned int*)(ws + 165412864); // 524288
  float* biasP = (float*)(ws + 165937152);    // 8192
  u16*   WclsP = (u16*)  (ws + 165945344);    // 49152
  u16*   outh  = (u16*)  (ws + 165994496);    // 33554432
  float* emiB  = (float*)(ws + 199548928);    // 4325376
  float* part  = (float*)(ws + 203874304);    // 512

  pack_all<<<18536, 256, 0, stream>>>(Wih_f, Wih_b, Whh_f, Whh_b, bih_f, bhh_f,
                                      bih_b, bhh_b, Wcls, batch_data, batch_onerad,
                                      embed, rad_embed, WihP, WhhF8, biasP, WclsP, Apack);
  gemm_xg<<<4096, 256, 0, stream>>>(Apack, WihP, biasP, X2);
  lstm_recur<<<128, 512, 0, stream>>>(X2, (const unsigned char*)WhhF8, outh);
  emis_k<<<512, 256, 0, stream>>>(outh, WclsP, bcls, emiB);
  crf2_k<<<128, 64, 0, stream>>>(batch_tag, emiB, trans, part);
  fin_k<<<1, 64, 0, stream>>>(part, (float*)d_out);
}

// Round 20
// 484.793 us; speedup vs baseline: 1.7085x; 1.2058x over previous
//
#include <hip/hip_runtime.h>
#include <hip/hip_bf16.h>
#include <stdint.h>

// LSTM-CRF forward loss. B=128 L=256 V=6000 E=128 RV=300 RD=100 H=256 C=33
// DIN=428 (pad to 448). Pipeline:
//   pack_all (weights+A; Whh as MX K=128 frags) -> gemm_xg (pair-contiguous X2)
//   -> lstm_recur (128 wg x 512 thr; 2-row chunks; 1 output/lane;
//      mfma_scale 16x16x128 fp8, scales=1.0 -> 16 MFMA/wave/step)
//   -> emis_k -> crf2_k -> fin_k

typedef unsigned short u16;
typedef __attribute__((ext_vector_type(8))) __bf16 bf16x8;
typedef __attribute__((ext_vector_type(4))) float f32x4;
typedef __attribute__((ext_vector_type(8))) int i32x8;
typedef __attribute__((ext_vector_type(4))) int i32x4;

struct __align__(8) u16x4 { u16 x, y, z, w; };

typedef const void __attribute__((address_space(1))) gas_t;
typedef void __attribute__((address_space(3))) las_t;

static __device__ __forceinline__ void gload16(const void* g, void* l) {
  __builtin_amdgcn_global_load_lds((gas_t*)g, (las_t*)l, 16, 0, 0);
}

static __device__ __forceinline__ u16 f2b(float x) {
  uint32_t u = __builtin_bit_cast(uint32_t, x);
  uint32_t r = u + 0x7fffu + ((u >> 16) & 1u);
  return (u16)(r >> 16);
}
static __device__ __forceinline__ float b2lo(uint32_t u) {
  return __builtin_bit_cast(float, u << 16);
}
static __device__ __forceinline__ float b2hi(uint32_t u) {
  return __builtin_bit_cast(float, u & 0xffff0000u);
}
static __device__ __forceinline__ uint32_t pkbf16(float lo, float hi) {
  uint32_t w;
  asm("v_cvt_pk_bf16_f32 %0, %1, %2" : "=v"(w) : "v"(lo), "v"(hi));
  return w;
}
static __device__ __forceinline__ float sigf(float x) {
  return __builtin_amdgcn_rcpf(1.f + __expf(-x));
}
static __device__ __forceinline__ float tanh_(float x) {
  return 1.f - 2.f * __builtin_amdgcn_rcpf(1.f + __expf(2.f * x));
}
static __device__ __forceinline__ f32x4 MFMA(bf16x8 a, bf16x8 b, f32x4 c) {
  return __builtin_amdgcn_mfma_f32_16x16x32_bf16(a, b, c, 0, 0, 0);
}

// ---------------- pack_all: weights (blocks < 4200) + A gather (rest) ----------------
// WhhF8 (MX layout): 256 frags of 2048 B. frag f = ((d*8+v)*8 + u)*2 + kt,
// u = gate*2+jf. Within frag: lane*32 + e, e in [0,32):
//   source Whh_d[gcol = gate*256+v*32+jf*16+(lane&15)][k = kt*128+(lane>>4)*32+e]
__global__ __launch_bounds__(256) void pack_all(
    const float* __restrict__ Wih_f, const float* __restrict__ Wih_b,
    const float* __restrict__ Whh_f, const float* __restrict__ Whh_b,
    const float* __restrict__ bih_f, const float* __restrict__ bhh_f,
    const float* __restrict__ bih_b, const float* __restrict__ bhh_b,
    const float* __restrict__ Wcls,
    const int* __restrict__ data, const int* __restrict__ onerad,
    const float* __restrict__ embed, const float* __restrict__ rad,
    u16* __restrict__ WihP, unsigned int* __restrict__ WhhF8,
    float* __restrict__ biasP, u16* __restrict__ WclsP, u16* __restrict__ A) {
  if (blockIdx.x < 4200) {
    int idx = blockIdx.x * 256 + threadIdx.x;
    if (idx < 917504) {                       // 2*1024*448
      int d = idx / 458752;
      int rem = idx - d * 458752;
      int r = rem / 448, k = rem - r * 448;
      const float* W = d ? Wih_b : Wih_f;
      WihP[idx] = (k < 428) ? f2b(W[r * 428 + k]) : (u16)0;
    } else if (idx < 919552) {                // bias 2048
      int j = idx - 917504;
      int r = j & 1023;
      biasP[j] = (j >> 10) ? (bih_b[r] + bhh_b[r]) : (bih_f[r] + bhh_f[r]);
    } else if (idx < 944128) {                // Wcls 48*512
      int j = idx - 919552;
      int r = j >> 9, k = j & 511;
      WclsP[j] = (r < 33) ? f2b(Wcls[r * 512 + k]) : (u16)0;
    } else if (idx < 1075200) {               // WhhF8: 131072 dwords (MX frags)
      int q = idx - 944128;
      int f = q >> 9;                 // frag 0..255
      int kt = f & 1, u = (f >> 1) & 7, v = (f >> 4) & 7, dd = f >> 7;
      int w9 = q & 511;
      int lane = w9 >> 3;
      int eb = (w9 & 7) * 4;
      int gate = u >> 1, jf = u & 1;
      int gcol = gate * 256 + v * 32 + jf * 16 + (lane & 15);
      int k = kt * 128 + (lane >> 4) * 32 + eb;
      const float* W = dd ? Whh_b : Whh_f;
      float4 fv4 = *(const float4*)(W + (size_t)gcol * 256 + k);
      unsigned int r01 = __builtin_amdgcn_cvt_pk_fp8_f32(fv4.x, fv4.y, 0u, false) & 0xffffu;
      unsigned int r23 = __builtin_amdgcn_cvt_pk_fp8_f32(fv4.z, fv4.w, 0u, false) & 0xffffu;
      WhhF8[q] = r01 | (r23 << 16);
    }
  } else {
    int idx = (blockIdx.x - 4200) * 256 + threadIdx.x;   // 32768*112 total
    int m = idx / 112;
    int c = idx - m * 112;
    int k0 = c * 4;
    float4 vv;
    if (k0 < 128)      vv = *(const float4*)(embed + (size_t)data[m] * 128 + k0);
    else if (k0 < 228) vv = *(const float4*)(rad + (size_t)onerad[m] * 100 + (k0 - 128));
    else if (k0 < 328) vv = *(const float4*)(rad + (size_t)onerad[32768 + m] * 100 + (k0 - 228));
    else if (k0 < 428) vv = *(const float4*)(rad + (size_t)onerad[65536 + m] * 100 + (k0 - 328));
    else               vv = make_float4(0.f, 0.f, 0.f, 0.f);
    u16x4 o4 = { f2b(vv.x), f2b(vv.y), f2b(vv.z), f2b(vv.w) };
    *(u16x4*)(A + (size_t)m * 448 + k0) = o4;
  }
}

// ---------------- xg GEMM: X2 = pair-contiguous(A @ Wih^T + bias) ----------------
// X2 u16 layout per d (33554432 u16): idx = R*1024 + gate*256 + v*32 + l16*2 + jf.
__global__ __launch_bounds__(256) void gemm_xg(const u16* __restrict__ A,
    const u16* __restrict__ Bw, const float* __restrict__ bias,
    u16* __restrict__ X2) {
  __shared__ u16 As[4096];
  __shared__ u16 Bs[4096];
  int bid = blockIdx.x;
  int mt = bid >> 4, nt = bid & 15;
  int m0 = mt * 128, n0 = nt * 128;
  int tid = threadIdx.x;
  int w = tid >> 6, lane = tid & 63, l16 = lane & 15, g = lane >> 4;
  int wr = w >> 1, wc = w & 1;
  int srow = tid >> 2, sch = tid & 3;
  f32x4 zero4 = {0.f, 0.f, 0.f, 0.f};
  f32x4 acc[4][4];
#pragma unroll
  for (int i = 0; i < 4; ++i)
#pragma unroll
    for (int j = 0; j < 4; ++j) acc[i][j] = zero4;
  for (int kk = 0; kk < 14; ++kk) {
    int kb = kk * 32;
    gload16(A + (size_t)(m0 + srow) * 448 + kb + sch * 8, (char*)As + tid * 16);
    gload16(A + (size_t)(m0 + srow + 64) * 448 + kb + sch * 8, (char*)As + 4096 + tid * 16);
    gload16(Bw + (size_t)(n0 + srow) * 448 + kb + sch * 8, (char*)Bs + tid * 16);
    gload16(Bw + (size_t)(n0 + srow + 64) * 448 + kb + sch * 8, (char*)Bs + 4096 + tid * 16);
    __syncthreads();
    bf16x8 af[4], bfr[4];
#pragma unroll
    for (int i = 0; i < 4; ++i) {
      af[i]  = *(const bf16x8*)((const char*)As + (wr * 64 + i * 16 + l16) * 64 + g * 16);
      bfr[i] = *(const bf16x8*)((const char*)Bs + (wc * 64 + i * 16 + l16) * 64 + g * 16);
    }
#pragma unroll
    for (int i = 0; i < 4; ++i)
#pragma unroll
      for (int j = 0; j < 4; ++j)
        acc[i][j] = MFMA(af[i], bfr[j], acc[i][j]);
    __syncthreads();
  }
  float bv[4];
#pragma unroll
  for (int j = 0; j < 4; ++j) bv[j] = bias[n0 + wc * 64 + j * 16 + l16];
  int dd = n0 >> 10;
#pragma unroll
  for (int i = 0; i < 4; ++i)
#pragma unroll
    for (int jp = 0; jp < 2; ++jp) {
      int j0 = jp * 2;
      int c = (n0 + wc * 64 + j0 * 16 + l16) & 1023;   // jf=0 member
      int gate = c >> 8, vv = (c >> 5) & 7, lc = c & 15;
      size_t base = (size_t)dd * 33554432 + (size_t)gate * 256 + vv * 32 + lc * 2;
#pragma unroll
      for (int r = 0; r < 4; ++r) {
        int row = m0 + wr * 64 + i * 16 + g * 4 + r;
        *(unsigned int*)(X2 + base + (size_t)row * 1024) =
            pkbf16(acc[i][j0][r] + bv[j0], acc[i][j0 + 1][r] + bv[j0 + 1]);
      }
    }
}

// ---------------- LSTM recurrence: 128 blocks, 2-row chunks, MX K=128 MFMA ----------------
// 128 blocks (2 dir x 64 chunks of 2 batch rows) x 512 thr. Wave v owns
// gate-cols {gate*256+v*32+jf*16+[0,16)} (u = gate*2+jf, 8 tiles), K=256 as
// 2 x K=128 scaled MFMAs per tile -> 16 MFMA/wave/step. Whh in 16 i32x8
// register frags (128 VGPR). h in LDS [16][256] fp8 with (row&7)<<4 XOR
// swizzle; lane owns ONE output (row = lane>>5, col = v*32+jf*16+l16).
#define MXM(u, Af, Bf) \
  acc[u] = __builtin_amdgcn_mfma_scale_f32_16x16x128_f8f6f4( \
      Af, Bf, acc[u], 0, 0, 0, 0x7F7F7F7Fu, 0, 0x7F7F7F7Fu);
// GVAL(gate): gate pre-activation for this lane's (row, col), + xg from px
#define GVAL(gate, dst) { \
  float a00 = __shfl(acc[(gate) * 2][0],     srcl); \
  float a01 = __shfl(acc[(gate) * 2][1],     srcl); \
  float a10 = __shfl(acc[(gate) * 2 + 1][0], srcl); \
  float a11 = __shfl(acc[(gate) * 2 + 1][1], srcl); \
  float s0 = hirow ? a01 : a00; \
  float s1 = hirow ? a11 : a10; \
  float xv = hijf ? b2hi(pxA[gate]) : b2lo(pxA[gate]); \
  dst = (hijf ? s1 : s0) + xv; }
#define FENCE { __builtin_amdgcn_sched_barrier(0); \
  asm volatile("s_waitcnt lgkmcnt(0)"); \
  __builtin_amdgcn_s_barrier(); \
  __builtin_amdgcn_sched_barrier(0); }

__global__ __launch_bounds__(512, 1) void lstm_recur(const u16* __restrict__ xg,
    const unsigned char* __restrict__ WhhF8, u16* __restrict__ outh) {
  __shared__ unsigned char hfA[2][4096];   // [16 rows][256 k] fp8, XOR-swizzled
  int blk = blockIdx.x;
  int d = blk >> 6, ch = blk & 63;
  int rowA0 = ch * 2;
  int tid = threadIdx.x;
  int v = tid >> 6, lane = tid & 63, l16 = lane & 15;
  int row = lane >> 5;           // output row 0/1
  int jf = (lane >> 4) & 1;
  bool hirow = (row == 1), hijf = (jf == 1);
  int srcl = l16;
  int col = v * 32 + jf * 16 + l16;

  // B fragments: 16 x i32x8 (u = gate*2+jf in [0,8), kt in [0,2); idx 2u+kt)
  const char* wb = (const char*)WhhF8 + (size_t)(d * 8 + v) * 32768 + (size_t)lane * 32;
  i32x8 bf0  = *(const i32x8*)(wb);
  i32x8 bf1  = *(const i32x8*)(wb + 2048);
  i32x8 bf2  = *(const i32x8*)(wb + 4096);
  i32x8 bf3  = *(const i32x8*)(wb + 6144);
  i32x8 bf4  = *(const i32x8*)(wb + 8192);
  i32x8 bf5  = *(const i32x8*)(wb + 10240);
  i32x8 bf6  = *(const i32x8*)(wb + 12288);
  i32x8 bf7  = *(const i32x8*)(wb + 14336);
  i32x8 bf8  = *(const i32x8*)(wb + 16384);
  i32x8 bf9  = *(const i32x8*)(wb + 18432);
  i32x8 bf10 = *(const i32x8*)(wb + 20480);
  i32x8 bf11 = *(const i32x8*)(wb + 22528);
  i32x8 bf12 = *(const i32x8*)(wb + 24576);
  i32x8 bf13 = *(const i32x8*)(wb + 26624);
  i32x8 bf14 = *(const i32x8*)(wb + 28672);
  i32x8 bf15 = *(const i32x8*)(wb + 30720);
  asm volatile("" :: "v"(bf0), "v"(bf1), "v"(bf2), "v"(bf3), "v"(bf4),
               "v"(bf5), "v"(bf6), "v"(bf7), "v"(bf8), "v"(bf9), "v"(bf10),
               "v"(bf11), "v"(bf12), "v"(bf13), "v"(bf14), "v"(bf15));

  for (int i = tid; i < 2048; i += 512) ((int*)hfA)[i] = 0;

  // A-frag LDS offsets (per lane): arow = lane&15, k-block (lane>>4)*32
  int arow = lane & 15;
  int sw = (arow & 7) << 4;
  int kb = (lane >> 4) * 32;
  int o0 = arow * 256 + ((kb) ^ sw);
  int o1 = arow * 256 + ((kb + 16) ^ sw);
  int o2 = arow * 256 + ((kb + 128) ^ sw);
  int o3 = arow * 256 + ((kb + 144) ^ sw);

  int t0 = d ? 255 : 0;
  int tpx = d ? -2048 : 2048;    // bytes per t-step in X2 (1024 u16/row-step)
  int tob = d ? -1024 : 1024;    // bytes per t-step in outh (512 u16)

  const char* pb = (const char*)xg + (size_t)d * 67108864
      + ((size_t)(rowA0 + row) * 256 + t0) * 2048 + v * 64 + l16 * 4;
  char* sb = (char*)outh
      + (((size_t)(rowA0 + row) * 256 + t0) * 512 + d * 256 + col) * 2;
  int fwoff = row * 256 + (col ^ (row << 4));   // row&7 == row (0/1)

  unsigned int pxA[4];
  pxA[0] = *(const unsigned int*)(pb);
  pxA[1] = *(const unsigned int*)(pb + 512);
  pxA[2] = *(const unsigned int*)(pb + 1024);
  pxA[3] = *(const unsigned int*)(pb + 1536);

  asm volatile("s_waitcnt vmcnt(0)" ::: "memory");
  __builtin_amdgcn_sched_barrier(0);

  f32x4 zero4 = {0.f, 0.f, 0.f, 0.f};
  float cst = 0.f;
  f32x4 acc[8];
  __syncthreads();

#pragma unroll 1
  for (int tt = 0; tt < 256; ++tt) {
    int p = tt & 1;
    // MFMA phase: 4 x b128 A-reads, then 16 scaled MFMAs
    {
      const unsigned char* hb = &hfA[p][0];
      i32x4 a0 = *(const i32x4*)(hb + o0);
      i32x4 a1 = *(const i32x4*)(hb + o1);
      i32x4 a2 = *(const i32x4*)(hb + o2);
      i32x4 a3 = *(const i32x4*)(hb + o3);
      asm volatile("s_waitcnt lgkmcnt(0)");
      __builtin_amdgcn_sched_barrier(0);
      i32x8 A0 = {a0[0], a0[1], a0[2], a0[3], a1[0], a1[1], a1[2], a1[3]};
      i32x8 A1 = {a2[0], a2[1], a2[2], a2[3], a3[0], a3[1], a3[2], a3[3]};
      acc[0] = zero4; acc[1] = zero4; acc[2] = zero4; acc[3] = zero4;
      acc[4] = zero4; acc[5] = zero4; acc[6] = zero4; acc[7] = zero4;
      MXM(0, A0, bf0)  MXM(1, A0, bf2)  MXM(2, A0, bf4)  MXM(3, A0, bf6)
      MXM(4, A0, bf8)  MXM(5, A0, bf10) MXM(6, A0, bf12) MXM(7, A0, bf14)
      MXM(0, A1, bf1)  MXM(1, A1, bf3)  MXM(2, A1, bf5)  MXM(3, A1, bf7)
      MXM(4, A1, bf9)  MXM(5, A1, bf11) MXM(6, A1, bf13) MXM(7, A1, bf15)
    }
    // TRANS: one output per lane
    {
      float iv, fv, gv, ov;
      GVAL(0, iv) GVAL(1, fv) GVAL(2, gv) GVAL(3, ov)
      float cn = sigf(fv) * cst + sigf(iv) * tanh_(gv);
      cst = cn;
      float hv = sigf(ov) * tanh_(cn);
      hfA[p ^ 1][fwoff] =
          (unsigned char)__builtin_amdgcn_cvt_pk_fp8_f32(hv, hv, 0u, false);
      *(u16*)sb = f2b(hv);
    }
    sb += tob; pb += tpx;
    pxA[0] = *(const unsigned int*)(pb);
    pxA[1] = *(const unsigned int*)(pb + 512);
    pxA[2] = *(const unsigned int*)(pb + 1024);
    pxA[3] = *(const unsigned int*)(pb + 1536);
    FENCE;
  }
}

// ---------------- emission: [32768][33] f32 = outh @ Wcls^T + bcls ----------------
__global__ __launch_bounds__(256) void emis_k(const u16* __restrict__ outh,
    const u16* __restrict__ WclsP, const float* __restrict__ bcls,
    float* __restrict__ emiB) {
  int tid = threadIdx.x;
  int w = tid >> 6, lane = tid & 63, l16 = lane & 15, g = lane >> 4;
  int mrow = blockIdx.x * 64 + w * 16;
  f32x4 zero4 = {0.f, 0.f, 0.f, 0.f};
  f32x4 acc[3] = {zero4, zero4, zero4};
#pragma unroll
  for (int kf = 0; kf < 16; ++kf) {
    bf16x8 a = *(const bf16x8*)(outh + (size_t)(mrow + l16) * 512 + kf * 32 + g * 8);
#pragma unroll
    for (int nf = 0; nf < 3; ++nf) {
      bf16x8 bb = *(const bf16x8*)(WclsP + (size_t)(nf * 16 + l16) * 512 + kf * 32 + g * 8);
      acc[nf] = MFMA(a, bb, acc[nf]);
    }
  }
#pragma unroll
  for (int nf = 0; nf < 3; ++nf) {
    int c = nf * 16 + l16;
    if (c < 33) {
      float bc = bcls[c];
#pragma unroll
      for (int r = 0; r < 4; ++r)
        emiB[(size_t)(mrow + g * 4 + r) * 33 + c] = acc[nf][r] + bc;
    }
  }
}

// ---------------- CRF forward + golden, fused; emissions LDS-resident ----------------
__global__ __launch_bounds__(64) void crf2_k(const int* __restrict__ tag,
    const float* __restrict__ emiB, const float* __restrict__ T,
    float* __restrict__ part) {
  int b = blockIdx.x;
  int lane = threadIdx.x;
  __shared__ float Ts[1089];
  __shared__ float E[8448];
  __shared__ float sc[33];
  for (int i = lane; i < 1089; i += 64) Ts[i] = T[i];
  {
    const float* eb = emiB + (size_t)b * 8448;
    for (int i = lane; i < 8448; i += 64) E[i] = eb[i];
  }
  int cnt = 0;
  for (int i = lane; i < 256; i += 64) cnt += (tag[b * 256 + i] != 0) ? 1 : 0;
#pragma unroll
  for (int o = 1; o < 64; o <<= 1) cnt += __shfl_xor(cnt, o);
  int len = cnt;
  __syncthreads();
  float gval = 0.f;
  for (int l = lane; l < 256; l += 64) {
    int tg = tag[b * 256 + l];
    if (tg != 0) {
      int prev = (l == 0) ? 31 : tag[b * 256 + l - 1];
      gval += E[l * 33 + tg] + Ts[prev * 33 + tg];
    }
  }
#pragma unroll
  for (int o = 32; o > 0; o >>= 1) gval += __shfl_down(gval, o);
  int c = lane;
  float tcol[33];
  if (c < 33) {
#pragma unroll
    for (int p = 0; p < 33; ++p) tcol[p] = Ts[p * 33 + c];
    sc[c] = E[c] + tcol[31];   // START=31
  }
  __syncthreads();
#pragma unroll 1
  for (int t = 1; t < len; ++t) {
    float nv = 0.f;
    if (c < 33) {
      float ec = E[t * 33 + c];
      float vb[33];
      float m0 = -3.0e38f, m1 = -3.0e38f, m2 = -3.0e38f, m3 = -3.0e38f;
#pragma unroll
      for (int p = 0; p < 32; p += 4) {
        vb[p]     = sc[p]     + tcol[p];     m0 = fmaxf(m0, vb[p]);
        vb[p + 1] = sc[p + 1] + tcol[p + 1]; m1 = fmaxf(m1, vb[p + 1]);
        vb[p + 2] = sc[p + 2] + tcol[p + 2]; m2 = fmaxf(m2, vb[p + 2]);
        vb[p + 3] = sc[p + 3] + tcol[p + 3]; m3 = fmaxf(m3, vb[p + 3]);
      }
      vb[32] = sc[32] + tcol[32];
      float mx = fmaxf(fmaxf(fmaxf(m0, m1), fmaxf(m2, m3)), vb[32]);
      float s0 = 0.f, s1 = 0.f, s2 = 0.f, s3 = 0.f;
#pragma unroll
      for (int p = 0; p < 32; p += 4) {
        s0 += __expf(vb[p] - mx);     s1 += __expf(vb[p + 1] - mx);
        s2 += __expf(vb[p + 2] - mx); s3 += __expf(vb[p + 3] - mx);
      }
      s0 += __expf(vb[32] - mx);
      nv = ec + mx + __logf((s0 + s1) + (s2 + s3));
    }
    __syncthreads();
    if (c < 33) sc[c] = nv;
    __syncthreads();
  }
  if (lane == 0) part[b] = sc[32] - gval;   // END=32
}

// ---------------- finalize: loss = sum(part) / 128 ----------------
__global__ __launch_bounds__(64) void fin_k(const float* __restrict__ part,
    float* __restrict__ out) {
  int l = threadIdx.x;
  float v = part[l] + part[l + 64];
#pragma unroll
  for (int o = 32; o > 0; o >>= 1) v += __shfl_down(v, o);
  if (l == 0) out[0] = v / 128.f;
}

extern "C" void kernel_launch(void* const* d_in, const int* in_sizes, int n_in,
                              void* d_out, int out_size, void* d_ws, size_t ws_size,
                              hipStream_t stream) {
  const int*   batch_data   = (const int*)d_in[0];
  const int*   batch_onerad = (const int*)d_in[1];
  const int*   batch_tag    = (const int*)d_in[2];
  const float* embed        = (const float*)d_in[3];
  const float* rad_embed    = (const float*)d_in[4];
  const float* Wih_f = (const float*)d_in[5];
  const float* Whh_f = (const float*)d_in[6];
  const float* bih_f = (const float*)d_in[7];
  const float* bhh_f = (const float*)d_in[8];
  const float* Wih_b = (const float*)d_in[9];
  const float* Whh_b = (const float*)d_in[10];
  const float* bih_b = (const float*)d_in[11];
  const float* bhh_b = (const float*)d_in[12];
  const float* Wcls  = (const float*)d_in[13];
  const float* bcls  = (const float*)d_in[14];
  const float* trans = (const float*)d_in[15];

  // workspace layout (~203.9 MB)
  char* ws = (char*)d_ws;
  u16*   Apack = (u16*)  (ws + 0);            // 29360128
  u16*   X2    = (u16*)  (ws + 29360128);     // 134217728 (pair-contiguous xg)
  u16*   WihP  = (u16*)  (ws + 163577856);    // 1835008
  unsigned int* WhhF8 = (unsigned int*)(ws + 165412864); // 524288 (MX frags)
  float* biasP = (float*)(ws + 165937152);    // 8192
  u16*   WclsP = (u16*)  (ws + 165945344);    // 49152
  u16*   outh  = (u16*)  (ws + 165994496);    // 33554432
  float* emiB  = (float*)(ws + 199548928);    // 4325376
  float* part  = (float*)(ws + 203874304);    // 512

  pack_all<<<18536, 256, 0, stream>>>(Wih_f, Wih_b, Whh_f, Whh_b, bih_f, bhh_f,
                                      bih_b, bhh_b, Wcls, batch_data, batch_onerad,
                                      embed, rad_embed, WihP, WhhF8, biasP, WclsP, Apack);
  gemm_xg<<<4096, 256, 0, stream>>>(Apack, WihP, biasP, X2);
  lstm_recur<<<128, 512, 0, stream>>>(X2, (const unsigned char*)WhhF8, outh);
  emis_k<<<512, 256, 0, stream>>>(outh, WclsP, bcls, emiB);
  crf2_k<<<128, 64, 0, stream>>>(batch_tag, emiB, trans, part);
  fin_k<<<1, 64, 0, stream>>>(part, (float*)d_out);
}

// Round 22
// 457.303 us; speedup vs baseline: 1.8112x; 1.0601x over previous
//
#include <hip/hip_runtime.h>
#include <hip/hip_bf16.h>
#include <stdint.h>

// LSTM-CRF forward loss. B=128 L=256 V=6000 E=128 RV=300 RD=100 H=256 C=33
// DIN=428 (pad to 512 fp8). Pipeline:
//   pack_all (W8/A8 fp8 pre-swizzled, Whh MX frags, bias, Wcls)
//   -> gemm_xg (MX K=128 fp8, 64 MXM/wave, pair-contiguous X2)
//   -> lstm_recur (128 wg; MX K=128; 1 output/lane)  [r20, proven 242us]
//   -> emis_k -> crf2_k -> fin_k

typedef unsigned short u16;
typedef __attribute__((ext_vector_type(8))) __bf16 bf16x8;
typedef __attribute__((ext_vector_type(4))) float f32x4;
typedef __attribute__((ext_vector_type(8))) int i32x8;
typedef __attribute__((ext_vector_type(4))) int i32x4;

struct __align__(8) u16x4 { u16 x, y, z, w; };

typedef const void __attribute__((address_space(1))) gas_t;
typedef void __attribute__((address_space(3))) las_t;

static __device__ __forceinline__ void gload16(const void* g, void* l) {
  __builtin_amdgcn_global_load_lds((gas_t*)g, (las_t*)l, 16, 0, 0);
}

static __device__ __forceinline__ u16 f2b(float x) {
  uint32_t u = __builtin_bit_cast(uint32_t, x);
  uint32_t r = u + 0x7fffu + ((u >> 16) & 1u);
  return (u16)(r >> 16);
}
static __device__ __forceinline__ float b2lo(uint32_t u) {
  return __builtin_bit_cast(float, u << 16);
}
static __device__ __forceinline__ float b2hi(uint32_t u) {
  return __builtin_bit_cast(float, u & 0xffff0000u);
}
static __device__ __forceinline__ uint32_t pkbf16(float lo, float hi) {
  uint32_t w;
  asm("v_cvt_pk_bf16_f32 %0, %1, %2" : "=v"(w) : "v"(lo), "v"(hi));
  return w;
}
static __device__ __forceinline__ uint32_t pkf8x4(float x, float y, float z, float w) {
  unsigned int r01 = __builtin_amdgcn_cvt_pk_fp8_f32(x, y, 0u, false) & 0xffffu;
  unsigned int r23 = __builtin_amdgcn_cvt_pk_fp8_f32(z, w, 0u, false) & 0xffffu;
  return r01 | (r23 << 16);
}
static __device__ __forceinline__ float sigf(float x) {
  return __builtin_amdgcn_rcpf(1.f + __expf(-x));
}
static __device__ __forceinline__ float tanh_(float x) {
  return 1.f - 2.f * __builtin_amdgcn_rcpf(1.f + __expf(2.f * x));
}
static __device__ __forceinline__ f32x4 MFMA(bf16x8 a, bf16x8 b, f32x4 c) {
  return __builtin_amdgcn_mfma_f32_16x16x32_bf16(a, b, c, 0, 0, 0);
}

// ---------------- pack_all ----------------
// W8 [2048][512] fp8, swizzled c^=(r&7)<<4; bias 2048 f32; WclsP [48][512] bf16;
// WhhF8 MX frags (131072 dwords, r20 layout); A8 [32768][512] fp8, swizzled.
__global__ __launch_bounds__(256) void pack_all(
    const float* __restrict__ Wih_f, const float* __restrict__ Wih_b,
    const float* __restrict__ Whh_f, const float* __restrict__ Whh_b,
    const float* __restrict__ bih_f, const float* __restrict__ bhh_f,
    const float* __restrict__ bih_b, const float* __restrict__ bhh_b,
    const float* __restrict__ Wcls,
    const int* __restrict__ data, const int* __restrict__ onerad,
    const float* __restrict__ embed, const float* __restrict__ rad,
    unsigned char* __restrict__ W8, unsigned int* __restrict__ WhhF8,
    float* __restrict__ biasP, u16* __restrict__ WclsP,
    unsigned char* __restrict__ A8) {
  if (blockIdx.x < 1640) {
    int idx = blockIdx.x * 256 + threadIdx.x;
    if (idx < 262144) {                       // W8: 2048 rows x 128 chunks
      int r = idx >> 7, c7 = idx & 127, k0 = c7 * 4;
      int d = r >> 10, rr = r & 1023;
      const float* W = d ? Wih_b : Wih_f;
      float4 f;
      if (k0 < 428) f = *(const float4*)(W + (size_t)rr * 428 + k0);
      else          f = make_float4(0.f, 0.f, 0.f, 0.f);
      *(unsigned int*)(W8 + (size_t)r * 512 + (k0 ^ ((r & 7) << 4))) =
          pkf8x4(f.x, f.y, f.z, f.w);
    } else if (idx < 264192) {                // bias 2048
      int j = idx - 262144;
      int r = j & 1023;
      biasP[j] = (j >> 10) ? (bih_b[r] + bhh_b[r]) : (bih_f[r] + bhh_f[r]);
    } else if (idx < 288768) {                // Wcls 48*512
      int j = idx - 264192;
      int r = j >> 9, k = j & 511;
      WclsP[j] = (r < 33) ? f2b(Wcls[r * 512 + k]) : (u16)0;
    } else if (idx < 419840) {                // WhhF8: 131072 dwords (MX frags)
      int q = idx - 288768;
      int f = q >> 9;                 // frag 0..255
      int kt = f & 1, u = (f >> 1) & 7, v = (f >> 4) & 7, dd = f >> 7;
      int w9 = q & 511;
      int lane = w9 >> 3;
      int eb = (w9 & 7) * 4;
      int gate = u >> 1, jf = u & 1;
      int gcol = gate * 256 + v * 32 + jf * 16 + (lane & 15);
      int k = kt * 128 + (lane >> 4) * 32 + eb;
      const float* W = dd ? Whh_b : Whh_f;
      float4 fv4 = *(const float4*)(W + (size_t)gcol * 256 + k);
      WhhF8[q] = pkf8x4(fv4.x, fv4.y, fv4.z, fv4.w);
    }
  } else {
    int idx = (blockIdx.x - 1640) * 256 + threadIdx.x;  // 32768*128 chunks
    int m = idx >> 7, c = idx & 127, k0 = c * 4;
    float4 vv;
    if (k0 < 128)      vv = *(const float4*)(embed + (size_t)data[m] * 128 + k0);
    else if (k0 < 228) vv = *(const float4*)(rad + (size_t)onerad[m] * 100 + (k0 - 128));
    else if (k0 < 328) vv = *(const float4*)(rad + (size_t)onerad[32768 + m] * 100 + (k0 - 228));
    else if (k0 < 428) vv = *(const float4*)(rad + (size_t)onerad[65536 + m] * 100 + (k0 - 328));
    else               vv = make_float4(0.f, 0.f, 0.f, 0.f);
    *(unsigned int*)(A8 + (size_t)m * 512 + (k0 ^ ((m & 7) << 4))) =
        pkf8x4(vv.x, vv.y, vv.z, vv.w);
  }
}

// ---------------- xg GEMM (MX fp8): X2 = pair-contiguous(A @ Wih^T + bias) ----------------
// 128x128 tile, BK=128, 4 waves (2x2 of 64x64), 64 mfma_scale_16x16x128/wave.
// Staging: 4 passes of o = p*4096 + tid*16 -> LDS dest is wave-uniform base +
// lane*16 (the global_load_lds HW constraint r21 violated); global source is
// per-lane (row = o>>7, colbyte = o&127). LDS linear [128][128]; frag reads
// 2x b128 with (row&7)<<4 XOR (2-way alias = free).
// X2 u16 layout per d (33554432 u16): idx = R*1024 + gate*256 + v*32 + l16*2 + jf.
#define GXM(i, j) \
  acc[i][j] = __builtin_amdgcn_mfma_scale_f32_16x16x128_f8f6f4( \
      af[i], bfj, acc[i][j], 0, 0, 0, 0x7F7F7F7Fu, 0, 0x7F7F7F7Fu);
__global__ __launch_bounds__(256, 2) void gemm_xg(const unsigned char* __restrict__ A8,
    const unsigned char* __restrict__ W8, const float* __restrict__ bias,
    u16* __restrict__ X2) {
  __shared__ unsigned char As[16384];   // [128][128]
  __shared__ unsigned char Bs[16384];
  int bid = blockIdx.x;
  int mt = bid >> 4, nt = bid & 15;
  int m0 = mt * 128, n0 = nt * 128;
  int tid = threadIdx.x;
  int w = tid >> 6, lane = tid & 63, l16 = lane & 15;
  int wr = w >> 1, wc = w & 1;
  int kc0 = (lane >> 4) * 32;
  f32x4 zero4 = {0.f, 0.f, 0.f, 0.f};
  f32x4 acc[4][4];
#pragma unroll
  for (int i = 0; i < 4; ++i)
#pragma unroll
    for (int j = 0; j < 4; ++j) acc[i][j] = zero4;
  for (int kk = 0; kk < 4; ++kk) {
    int kb = kk * 128;
#pragma unroll
    for (int ps = 0; ps < 4; ++ps) {
      int o = ps * 4096 + tid * 16;       // LDS dest: wave-uniform + lane*16
      int rs = o >> 7, cb = o & 127;      // global src: per-lane
      gload16(A8 + (size_t)(m0 + rs) * 512 + kb + cb, (char*)As + o);
      gload16(W8 + (size_t)(n0 + rs) * 512 + kb + cb, (char*)Bs + o);
    }
    __syncthreads();
    i32x8 af[4];
#pragma unroll
    for (int i = 0; i < 4; ++i) {
      int arow = wr * 64 + i * 16 + l16;
      int sw = (arow & 7) << 4;
      const unsigned char* ab = As + arow * 128;
      i32x4 x0 = *(const i32x4*)(ab + (kc0 ^ sw));
      i32x4 x1 = *(const i32x4*)(ab + ((kc0 + 16) ^ sw));
      af[i] = (i32x8){x0[0], x0[1], x0[2], x0[3], x1[0], x1[1], x1[2], x1[3]};
    }
#pragma unroll
    for (int j = 0; j < 4; ++j) {
      int brow = wc * 64 + j * 16 + l16;
      int sw = (brow & 7) << 4;
      const unsigned char* bb = Bs + brow * 128;
      i32x4 y0 = *(const i32x4*)(bb + (kc0 ^ sw));
      i32x4 y1 = *(const i32x4*)(bb + ((kc0 + 16) ^ sw));
      i32x8 bfj = (i32x8){y0[0], y0[1], y0[2], y0[3], y1[0], y1[1], y1[2], y1[3]};
      GXM(0, j) GXM(1, j) GXM(2, j) GXM(3, j)
    }
    __syncthreads();
  }
  float bv[4];
#pragma unroll
  for (int j = 0; j < 4; ++j) bv[j] = bias[n0 + wc * 64 + j * 16 + l16];
  int dd = n0 >> 10;
  int g = lane >> 4;
#pragma unroll
  for (int i = 0; i < 4; ++i)
#pragma unroll
    for (int jp = 0; jp < 2; ++jp) {
      int j0 = jp * 2;
      int c = (n0 + wc * 64 + j0 * 16 + l16) & 1023;   // jf=0 member
      int gate = c >> 8, vv = (c >> 5) & 7, lc = c & 15;
      size_t base = (size_t)dd * 33554432 + (size_t)gate * 256 + vv * 32 + lc * 2;
#pragma unroll
      for (int r = 0; r < 4; ++r) {
        int row = m0 + wr * 64 + i * 16 + g * 4 + r;
        *(unsigned int*)(X2 + base + (size_t)row * 1024) =
            pkbf16(acc[i][j0][r] + bv[j0], acc[i][j0 + 1][r] + bv[j0 + 1]);
      }
    }
}

// ---------------- LSTM recurrence: 128 blocks, 2-row chunks, MX K=128 MFMA ----------------
// r20, proven 242us. Wave v owns gate-cols {gate*256+v*32+jf*16+[0,16)}
// (u = gate*2+jf, 8 tiles), K=256 as 2 x K=128 scaled MFMAs per tile ->
// 16 MFMA/wave/step. Whh in 16 i32x8 register frags. h in LDS [16][256] fp8
// XOR-swizzled; lane owns ONE output (row = lane>>5, col = v*32+jf*16+l16).
#define MXM(u, Af, Bf) \
  acc[u] = __builtin_amdgcn_mfma_scale_f32_16x16x128_f8f6f4( \
      Af, Bf, acc[u], 0, 0, 0, 0x7F7F7F7Fu, 0, 0x7F7F7F7Fu);
#define GVAL(gate, dst) { \
  float a00 = __shfl(acc[(gate) * 2][0],     srcl); \
  float a01 = __shfl(acc[(gate) * 2][1],     srcl); \
  float a10 = __shfl(acc[(gate) * 2 + 1][0], srcl); \
  float a11 = __shfl(acc[(gate) * 2 + 1][1], srcl); \
  float s0 = hirow ? a01 : a00; \
  float s1 = hirow ? a11 : a10; \
  float xv = hijf ? b2hi(pxA[gate]) : b2lo(pxA[gate]); \
  dst = (hijf ? s1 : s0) + xv; }
#define FENCE { __builtin_amdgcn_sched_barrier(0); \
  asm volatile("s_waitcnt lgkmcnt(0)"); \
  __builtin_amdgcn_s_barrier(); \
  __builtin_amdgcn_sched_barrier(0); }

__global__ __launch_bounds__(512, 1) void lstm_recur(const u16* __restrict__ xg,
    const unsigned char* __restrict__ WhhF8, u16* __restrict__ outh) {
  __shared__ unsigned char hfA[2][4096];   // [16 rows][256 k] fp8, XOR-swizzled
  int blk = blockIdx.x;
  int d = blk >> 6, ch = blk & 63;
  int rowA0 = ch * 2;
  int tid = threadIdx.x;
  int v = tid >> 6, lane = tid & 63, l16 = lane & 15;
  int row = lane >> 5;           // output row 0/1
  int jf = (lane >> 4) & 1;
  bool hirow = (row == 1), hijf = (jf == 1);
  int srcl = l16;
  int col = v * 32 + jf * 16 + l16;

  const char* wb = (const char*)WhhF8 + (size_t)(d * 8 + v) * 32768 + (size_t)lane * 32;
  i32x8 bf0  = *(const i32x8*)(wb);
  i32x8 bf1  = *(const i32x8*)(wb + 2048);
  i32x8 bf2  = *(const i32x8*)(wb + 4096);
  i32x8 bf3  = *(const i32x8*)(wb + 6144);
  i32x8 bf4  = *(const i32x8*)(wb + 8192);
  i32x8 bf5  = *(const i32x8*)(wb + 10240);
  i32x8 bf6  = *(const i32x8*)(wb + 12288);
  i32x8 bf7  = *(const i32x8*)(wb + 14336);
  i32x8 bf8  = *(const i32x8*)(wb + 16384);
  i32x8 bf9  = *(const i32x8*)(wb + 18432);
  i32x8 bf10 = *(const i32x8*)(wb + 20480);
  i32x8 bf11 = *(const i32x8*)(wb + 22528);
  i32x8 bf12 = *(const i32x8*)(wb + 24576);
  i32x8 bf13 = *(const i32x8*)(wb + 26624);
  i32x8 bf14 = *(const i32x8*)(wb + 28672);
  i32x8 bf15 = *(const i32x8*)(wb + 30720);
  asm volatile("" :: "v"(bf0), "v"(bf1), "v"(bf2), "v"(bf3), "v"(bf4),
               "v"(bf5), "v"(bf6), "v"(bf7), "v"(bf8), "v"(bf9), "v"(bf10),
               "v"(bf11), "v"(bf12), "v"(bf13), "v"(bf14), "v"(bf15));

  for (int i = tid; i < 2048; i += 512) ((int*)hfA)[i] = 0;

  int arow = lane & 15;
  int sw = (arow & 7) << 4;
  int kb = (lane >> 4) * 32;
  int o0 = arow * 256 + ((kb) ^ sw);
  int o1 = arow * 256 + ((kb + 16) ^ sw);
  int o2 = arow * 256 + ((kb + 128) ^ sw);
  int o3 = arow * 256 + ((kb + 144) ^ sw);

  int t0 = d ? 255 : 0;
  int tpx = d ? -2048 : 2048;    // bytes per t-step in X2 (1024 u16/row-step)
  int tob = d ? -1024 : 1024;    // bytes per t-step in outh (512 u16)

  const char* pb = (const char*)xg + (size_t)d * 67108864
      + ((size_t)(rowA0 + row) * 256 + t0) * 2048 + v * 64 + l16 * 4;
  char* sb = (char*)outh
      + (((size_t)(rowA0 + row) * 256 + t0) * 512 + d * 256 + col) * 2;
  int fwoff = row * 256 + (col ^ (row << 4));   // row&7 == row (0/1)

  unsigned int pxA[4];
  pxA[0] = *(const unsigned int*)(pb);
  pxA[1] = *(const unsigned int*)(pb + 512);
  pxA[2] = *(const unsigned int*)(pb + 1024);
  pxA[3] = *(const unsigned int*)(pb + 1536);

  asm volatile("s_waitcnt vmcnt(0)" ::: "memory");
  __builtin_amdgcn_sched_barrier(0);

  f32x4 zero4 = {0.f, 0.f, 0.f, 0.f};
  float cst = 0.f;
  f32x4 acc[8];
  __syncthreads();

#pragma unroll 1
  for (int tt = 0; tt < 256; ++tt) {
    int p = tt & 1;
    {
      const unsigned char* hb = &hfA[p][0];
      i32x4 a0 = *(const i32x4*)(hb + o0);
      i32x4 a1 = *(const i32x4*)(hb + o1);
      i32x4 a2 = *(const i32x4*)(hb + o2);
      i32x4 a3 = *(const i32x4*)(hb + o3);
      asm volatile("s_waitcnt lgkmcnt(0)");
      __builtin_amdgcn_sched_barrier(0);
      i32x8 A0 = {a0[0], a0[1], a0[2], a0[3], a1[0], a1[1], a1[2], a1[3]};
      i32x8 A1 = {a2[0], a2[1], a2[2], a2[3], a3[0], a3[1], a3[2], a3[3]};
      acc[0] = zero4; acc[1] = zero4; acc[2] = zero4; acc[3] = zero4;
      acc[4] = zero4; acc[5] = zero4; acc[6] = zero4; acc[7] = zero4;
      MXM(0, A0, bf0)  MXM(1, A0, bf2)  MXM(2, A0, bf4)  MXM(3, A0, bf6)
      MXM(4, A0, bf8)  MXM(5, A0, bf10) MXM(6, A0, bf12) MXM(7, A0, bf14)
      MXM(0, A1, bf1)  MXM(1, A1, bf3)  MXM(2, A1, bf5)  MXM(3, A1, bf7)
      MXM(4, A1, bf9)  MXM(5, A1, bf11) MXM(6, A1, bf13) MXM(7, A1, bf15)
    }
    {
      float iv, fv, gv, ov;
      GVAL(0, iv) GVAL(1, fv) GVAL(2, gv) GVAL(3, ov)
      float cn = sigf(fv) * cst + sigf(iv) * tanh_(gv);
      cst = cn;
      float hv = sigf(ov) * tanh_(cn);
      hfA[p ^ 1][fwoff] =
          (unsigned char)__builtin_amdgcn_cvt_pk_fp8_f32(hv, hv, 0u, false);
      *(u16*)sb = f2b(hv);
    }
    sb += tob; pb += tpx;
    pxA[0] = *(const unsigned int*)(pb);
    pxA[1] = *(const unsigned int*)(pb + 512);
    pxA[2] = *(const unsigned int*)(pb + 1024);
    pxA[3] = *(const unsigned int*)(pb + 1536);
    FENCE;
  }
}

// ---------------- emission: [32768][33] f32 = outh @ Wcls^T + bcls ----------------
__global__ __launch_bounds__(256) void emis_k(const u16* __restrict__ outh,
    const u16* __restrict__ WclsP, const float* __restrict__ bcls,
    float* __restrict__ emiB) {
  int tid = threadIdx.x;
  int w = tid >> 6, lane = tid & 63, l16 = lane & 15, g = lane >> 4;
  int mrow = blockIdx.x * 64 + w * 16;
  f32x4 zero4 = {0.f, 0.f, 0.f, 0.f};
  f32x4 acc[3] = {zero4, zero4, zero4};
#pragma unroll
  for (int kf = 0; kf < 16; ++kf) {
    bf16x8 a = *(const bf16x8*)(outh + (size_t)(mrow + l16) * 512 + kf * 32 + g * 8);
#pragma unroll
    for (int nf = 0; nf < 3; ++nf) {
      bf16x8 bb = *(const bf16x8*)(WclsP + (size_t)(nf * 16 + l16) * 512 + kf * 32 + g * 8);
      acc[nf] = MFMA(a, bb, acc[nf]);
    }
  }
#pragma unroll
  for (int nf = 0; nf < 3; ++nf) {
    int c = nf * 16 + l16;
    if (c < 33) {
      float bc = bcls[c];
#pragma unroll
      for (int r = 0; r < 4; ++r)
        emiB[(size_t)(mrow + g * 4 + r) * 33 + c] = acc[nf][r] + bc;
    }
  }
}

// ---------------- CRF forward + golden, fused; emissions LDS-resident ----------------
__global__ __launch_bounds__(64) void crf2_k(const int* __restrict__ tag,
    const float* __restrict__ emiB, const float* __restrict__ T,
    float* __restrict__ part) {
  int b = blockIdx.x;
  int lane = threadIdx.x;
  __shared__ float Ts[1089];
  __shared__ float E[8448];
  __shared__ float sc[33];
  for (int i = lane; i < 1089; i += 64) Ts[i] = T[i];
  {
    const float* eb = emiB + (size_t)b * 8448;
    for (int i = lane; i < 8448; i += 64) E[i] = eb[i];
  }
  int cnt = 0;
  for (int i = lane; i < 256; i += 64) cnt += (tag[b * 256 + i] != 0) ? 1 : 0;
#pragma unroll
  for (int o = 1; o < 64; o <<= 1) cnt += __shfl_xor(cnt, o);
  int len = cnt;
  __syncthreads();
  float gval = 0.f;
  for (int l = lane; l < 256; l += 64) {
    int tg = tag[b * 256 + l];
    if (tg != 0) {
      int prev = (l == 0) ? 31 : tag[b * 256 + l - 1];
      gval += E[l * 33 + tg] + Ts[prev * 33 + tg];
    }
  }
#pragma unroll
  for (int o = 32; o > 0; o >>= 1) gval += __shfl_down(gval, o);
  int c = lane;
  float tcol[33];
  if (c < 33) {
#pragma unroll
    for (int p = 0; p < 33; ++p) tcol[p] = Ts[p * 33 + c];
    sc[c] = E[c] + tcol[31];   // START=31
  }
  __syncthreads();
#pragma unroll 1
  for (int t = 1; t < len; ++t) {
    float nv = 0.f;
    if (c < 33) {
      float ec = E[t * 33 + c];
      float vb[33];
      float m0 = -3.0e38f, m1 = -3.0e38f, m2 = -3.0e38f, m3 = -3.0e38f;
#pragma unroll
      for (int p = 0; p < 32; p += 4) {
        vb[p]     = sc[p]     + tcol[p];     m0 = fmaxf(m0, vb[p]);
        vb[p + 1] = sc[p + 1] + tcol[p + 1]; m1 = fmaxf(m1, vb[p + 1]);
        vb[p + 2] = sc[p + 2] + tcol[p + 2]; m2 = fmaxf(m2, vb[p + 2]);
        vb[p + 3] = sc[p + 3] + tcol[p + 3]; m3 = fmaxf(m3, vb[p + 3]);
      }
      vb[32] = sc[32] + tcol[32];
      float mx = fmaxf(fmaxf(fmaxf(m0, m1), fmaxf(m2, m3)), vb[32]);
      float s0 = 0.f, s1 = 0.f, s2 = 0.f, s3 = 0.f;
#pragma unroll
      for (int p = 0; p < 32; p += 4) {
        s0 += __expf(vb[p] - mx);     s1 += __expf(vb[p + 1] - mx);
        s2 += __expf(vb[p + 2] - mx); s3 += __expf(vb[p + 3] - mx);
      }
      s0 += __expf(vb[32] - mx);
      nv = ec + mx + __logf((s0 + s1) + (s2 + s3));
    }
    __syncthreads();
    if (c < 33) sc[c] = nv;
    __syncthreads();
  }
  if (lane == 0) part[b] = sc[32] - gval;   // END=32
}

// ---------------- finalize: loss = sum(part) / 128 ----------------
__global__ __launch_bounds__(64) void fin_k(const float* __restrict__ part,
    float* __restrict__ out) {
  int l = threadIdx.x;
  float v = part[l] + part[l + 64];
#pragma unroll
  for (int o = 32; o > 0; o >>= 1) v += __shfl_down(v, o);
  if (l == 0) out[0] = v / 128.f;
}

extern "C" void kernel_launch(void* const* d_in, const int* in_sizes, int n_in,
                              void* d_out, int out_size, void* d_ws, size_t ws_size,
                              hipStream_t stream) {
  const int*   batch_data   = (const int*)d_in[0];
  const int*   batch_onerad = (const int*)d_in[1];
  const int*   batch_tag    = (const int*)d_in[2];
  const float* embed        = (const float*)d_in[3];
  const float* rad_embed    = (const float*)d_in[4];
  const float* Wih_f = (const float*)d_in[5];
  const float* Whh_f = (const float*)d_in[6];
  const float* bih_f = (const float*)d_in[7];
  const float* bhh_f = (const float*)d_in[8];
  const float* Wih_b = (const float*)d_in[9];
  const float* Whh_b = (const float*)d_in[10];
  const float* bih_b = (const float*)d_in[11];
  const float* bhh_b = (const float*)d_in[12];
  const float* Wcls  = (const float*)d_in[13];
  const float* bcls  = (const float*)d_in[14];
  const float* trans = (const float*)d_in[15];

  // workspace layout (~203.9 MB)
  char* ws = (char*)d_ws;
  unsigned char* A8 = (unsigned char*)(ws + 0);  // 32768*512 = 16777216
  u16*   X2    = (u16*)  (ws + 29360128);     // 134217728 (pair-contiguous xg)
  unsigned char* W8 = (unsigned char*)(ws + 163577856);  // 2048*512 = 1048576
  unsigned int* WhhF8 = (unsigned int*)(ws + 165412864); // 524288 (MX frags)
  float* biasP = (float*)(ws + 165937152);    // 8192
  u16*   WclsP = (u16*)  (ws + 165945344);    // 49152
  u16*   outh  = (u16*)  (ws + 165994496);    // 33554432
  float* emiB  = (float*)(ws + 199548928);    // 4325376
  float* part  = (float*)(ws + 203874304);    // 512

  pack_all<<<18024, 256, 0, stream>>>(Wih_f, Wih_b, Whh_f, Whh_b, bih_f, bhh_f,
                                      bih_b, bhh_b, Wcls, batch_data, batch_onerad,
                                      embed, rad_embed, W8, WhhF8, biasP, WclsP, A8);
  gemm_xg<<<4096, 256, 0, stream>>>(A8, W8, biasP, X2);
  lstm_recur<<<128, 512, 0, stream>>>(X2, (const unsigned char*)WhhF8, outh);
  emis_k<<<512, 256, 0, stream>>>(outh, WclsP, bcls, emiB);
  crf2_k<<<128, 64, 0, stream>>>(batch_tag, emiB, trans, part);
  fin_k<<<1, 64, 0, stream>>>(part, (float*)d_out);
}